// Round 6
// baseline (1039.696 us; speedup 1.0000x reference)
//
#include <hip/hip_runtime.h>
#include <stdint.h>

typedef unsigned short u16;
typedef unsigned int   u32;

#define NN 16384   // nodes
#define NE 262144  // edges
#define NG 64      // graphs
#define HD 256     // hidden
#define SHS 264    // row-major LDS tile stride in u16 (+8 pad -> 2-way-free banks)

typedef __attribute__((ext_vector_type(8))) short bfrag;  // 8 bf16 (4 VGPR)
typedef __attribute__((ext_vector_type(4))) float ffrag;  // 4 f32 acc

__device__ __forceinline__ float bf2f(u16 h){
  union { u32 u; float f; } v; v.u = ((u32)h) << 16; return v.f;
}
__device__ __forceinline__ u16 f2bf(float x){
  union { float f; u32 u; } v; v.f = x;
  u32 r = v.u + 0x7fffu + ((v.u >> 16) & 1u);
  return (u16)(r >> 16);
}
__device__ __forceinline__ float sigmoidf(float x){ return 1.f/(1.f+__expf(-x)); }

// async global->LDS DMA, 16B/lane: lane i lands at (wave-uniform base) + i*16
__device__ __forceinline__ void dma16(const void* g, void* l){
  __builtin_amdgcn_global_load_lds(
      (const __attribute__((address_space(1))) u32*)g,
      (__attribute__((address_space(3))) u32*)l, 16, 0, 0);
}

// Feature permutation pi: feature f lives at position p(f)=(f>>6)*64+(f&15)*4
// +((f>>4)&3); inv(p)=(p>>6)*64+(p&3)*16+((p>>2)&15). Weights repacked with
// K-rows permuted by inv(). Epilogues write packed uint2; P/Q gathers are one
// uint2 per row.
//
// R12: R11's inline-asm v_cvt_pk_bf16_f32 REVERTED everywhere (measured:
// mega VALUBusy 44->35 but dur 135->139 -- the asm constrained scheduling;
// matches the documented m240 result "don't hand-write cvt_pk"). Body is
// R10 (999us baseline: idx pre-stage + setprio + launch_bounds(256,4)),
// with ONE live change kept from R11: ibs_k fusing initbe+iter0-score
// (deletes a 134MB BE re-read). Clean isolation: if total ~999, drop ibs.

enum { MODE_SCORE=0, MODE_PQ=4 };

// SCORE: outF = sigmoid(relu(A@Bf0+bias)@vec + scal)  (per-row scalar)
// PQ (grid.y=0/1): out{0,1} = A@Bf{0,1} [+bias] + flag-rank1(ht{0,1})
template<int MODE>
__global__ __launch_bounds__(256, 4)
void gemm_k(const u16* __restrict__ A, const u16* __restrict__ Bf0,
            const u16* __restrict__ Bf1,
            float* __restrict__ outF, u16* __restrict__ out0, u16* __restrict__ out1,
            const float* __restrict__ bias, const float* __restrict__ vec,
            const float* __restrict__ scal, const float* __restrict__ flags,
            const float* __restrict__ ht0, const float* __restrict__ ht1)
{
  __shared__ __align__(16) u16 sA[16384];   // 32KB, frag layout [(c*4+mt)*512 + l*8]
  __shared__ float sred[4][64];

  const int l  = threadIdx.x & 63;
  const int w  = threadIdx.x >> 6;
  const int q  = l >> 4;
  const int ml = l & 15;
  const long rowBase = (long)blockIdx.x * 64;

  const u16* Bf   = Bf0;
  u16*       outB = out0;
  const float* htp = ht0;
  const float* bp  = bias;
  if (MODE==MODE_PQ && blockIdx.y){ Bf = Bf1; outB = out1; htp = ht1; bp = nullptr; }

  // stage A tile once (frag layout); init-acc loads fly under the staging drain
  const u16* gA = A + (size_t)(rowBase + w*16 + ml)*HD + q*8;
#pragma unroll
  for (int c=0; c<8; ++c) dma16(gA + c*32, sA + (c*4+w)*512);

  ffrag acc[4][4];
  if constexpr (MODE==MODE_SCORE){
#pragma unroll
    for (int n=0; n<4; ++n){
      const float bb = bias[(w*4+n)*16+ml];
#pragma unroll
      for (int mt=0; mt<4; ++mt) acc[mt][n] = (ffrag){bb,bb,bb,bb};
    }
  } else {
    float h0[4], h1[4], bb[4];
#pragma unroll
    for (int n=0; n<4; ++n){
      const int col = (w*4+n)*16+ml;
      h0[n] = htp[col]; h1[n] = htp[HD+col]; bb[n] = bp ? bp[col] : 0.f;
    }
    float2 fl[16];
#pragma unroll
    for (int i=0; i<16; ++i){
      long row = rowBase + (i>>2)*16 + q*4 + (i&3);
      fl[i] = *(const float2*)(flags + 2*row);
    }
#pragma unroll
    for (int i=0; i<16; ++i){
      const int mt = i>>2, r = i&3;
      const float fh = fl[i].x, ft = fl[i].y;
#pragma unroll
      for (int n=0; n<4; ++n)
        acc[mt][n][r] = bb[n] + fh*h0[n] + ft*h1[n];
    }
  }
  __syncthreads();

  __builtin_amdgcn_s_setprio(1);
#pragma unroll 1
  for (int c=0; c<8; ++c){
    bfrag a[4], b[4];
#pragma unroll
    for (int n=0; n<4; ++n)
      b[n] = *(const bfrag*)(Bf + (((size_t)c*16 + w*4 + n)*64 + l)*8);
#pragma unroll
    for (int mt=0; mt<4; ++mt) a[mt] = *(const bfrag*)(sA + (c*4+mt)*512 + l*8);
#pragma unroll
    for (int mt=0; mt<4; ++mt)
#pragma unroll
      for (int n=0; n<4; ++n)
        acc[mt][n] = __builtin_amdgcn_mfma_f32_16x16x32_bf16(a[mt], b[n], acc[mt][n], 0, 0, 0);
  }
  __builtin_amdgcn_s_setprio(0);

  if constexpr (MODE==MODE_SCORE){
    float part[4][4];
#pragma unroll
    for (int mt=0; mt<4; ++mt)
#pragma unroll
      for (int r=0; r<4; ++r) part[mt][r] = 0.f;
#pragma unroll
    for (int n=0; n<4; ++n){
      const float vvn = vec[(w*4+n)*16+ml];
#pragma unroll
      for (int mt=0; mt<4; ++mt)
#pragma unroll
        for (int r=0; r<4; ++r)
          part[mt][r] += fmaxf(acc[mt][n][r], 0.f) * vvn;   // bias in acc-init
    }
#pragma unroll
    for (int mt=0; mt<4; ++mt)
#pragma unroll
      for (int r=0; r<4; ++r){
        float p = part[mt][r];
        p += __shfl_xor(p, 1, 64); p += __shfl_xor(p, 2, 64);
        p += __shfl_xor(p, 4, 64); p += __shfl_xor(p, 8, 64);
        part[mt][r] = p;
      }
    if (ml == 0)
#pragma unroll
      for (int mt=0; mt<4; ++mt)
#pragma unroll
        for (int r=0; r<4; ++r)
          sred[w][mt*16 + q*4 + r] = part[mt][r];
    __syncthreads();
    if (threadIdx.x < 64){
      const int t = threadIdx.x;
      float v = sred[0][t] + sred[1][t] + sred[2][t] + sred[3][t];
      outF[rowBase + t] = sigmoidf(v + scal[0]);
    }
  } else { // MODE_PQ: all additive terms already in acc-init
#pragma unroll
    for (int mt=0; mt<4; ++mt)
#pragma unroll
      for (int r=0; r<4; ++r){
        long row = rowBase + mt*16 + q*4 + r;
        u16 o[4];
#pragma unroll
        for (int n=0; n<4; ++n) o[n] = f2bf(acc[mt][n][r]);
        uint2 pk; pk.x = (u32)o[0] | ((u32)o[1]<<16); pk.y = (u32)o[2] | ((u32)o[3]<<16);
        *(uint2*)(outB + (size_t)row*HD + w*64 + ml*4) = pk;
      }
  }
}

// ---- IBS: fused b_e init + iter0 score ----
// Builds the BE tile in LDS frag layout straight from ef/g_all (permuted
// positions), stores BE to HBM once, then score GEMM from the LDS tile.
__global__ __launch_bounds__(256, 4)
void ibs_k(const float* __restrict__ ef, const float* __restrict__ gall,
           u16* __restrict__ BE, const u16* __restrict__ eaw1f,
           float* __restrict__ outF,
           const float* __restrict__ bias, const float* __restrict__ vec,
           const float* __restrict__ scal)
{
  __shared__ __align__(16) u16 sA[16384];
  __shared__ float sred[4][64];

  const int l  = threadIdx.x & 63;
  const int w  = threadIdx.x >> 6;
  const int q  = l >> 4;
  const int ml = l & 15;
  const long rowBase = (long)blockIdx.x * 64;
  const long row = rowBase + w*16 + ml;
  const float* efr = ef + (size_t)row*192;

  ffrag acc[4][4];
#pragma unroll
  for (int n=0; n<4; ++n){
    const float bb = bias[(w*4+n)*16+ml];
#pragma unroll
    for (int mt=0; mt<4; ++mt) acc[mt][n] = (ffrag){bb,bb,bb,bb};
  }

  // build frag cells (c, mt=w): value at k-slot p=c*32+q*8+j is feature inv(p)
#pragma unroll
  for (int c=0; c<8; ++c){
    float v[8];
#pragma unroll
    for (int j=0; j<8; ++j){
      const int p = c*32 + q*8 + j;
      const int f = (p>>6)*64 + (p&3)*16 + ((p>>2)&15);   // inv(p)
      v[j] = (c < 6) ? efr[f] : gall[f - 192];
    }
    u16 o[8];
#pragma unroll
    for (int j=0; j<8; ++j) o[j] = f2bf(v[j]);
    uint4 pk;
    pk.x = (u32)o[0] | ((u32)o[1]<<16); pk.y = (u32)o[2] | ((u32)o[3]<<16);
    pk.z = (u32)o[4] | ((u32)o[5]<<16); pk.w = (u32)o[6] | ((u32)o[7]<<16);
    *(uint4*)(sA + (c*4+w)*512 + l*8) = pk;                      // LDS frag
    *(uint4*)(BE + (size_t)row*HD + c*32 + q*8) = pk;            // global, 16B
  }
  __syncthreads();

  __builtin_amdgcn_s_setprio(1);
#pragma unroll 1
  for (int c=0; c<8; ++c){
    bfrag a[4], b[4];
#pragma unroll
    for (int n=0; n<4; ++n)
      b[n] = *(const bfrag*)(eaw1f + (((size_t)c*16 + w*4 + n)*64 + l)*8);
#pragma unroll
    for (int mt=0; mt<4; ++mt) a[mt] = *(const bfrag*)(sA + (c*4+mt)*512 + l*8);
#pragma unroll
    for (int mt=0; mt<4; ++mt)
#pragma unroll
      for (int n=0; n<4; ++n)
        acc[mt][n] = __builtin_amdgcn_mfma_f32_16x16x32_bf16(a[mt], b[n], acc[mt][n], 0, 0, 0);
  }
  __builtin_amdgcn_s_setprio(0);

  float part[4][4];
#pragma unroll
  for (int mt=0; mt<4; ++mt)
#pragma unroll
    for (int r=0; r<4; ++r) part[mt][r] = 0.f;
#pragma unroll
  for (int n=0; n<4; ++n){
    const float vvn = vec[(w*4+n)*16+ml];
#pragma unroll
    for (int mt=0; mt<4; ++mt)
#pragma unroll
      for (int r=0; r<4; ++r)
        part[mt][r] += fmaxf(acc[mt][n][r], 0.f) * vvn;   // bias in acc-init
  }
#pragma unroll
  for (int mt=0; mt<4; ++mt)
#pragma unroll
    for (int r=0; r<4; ++r){
      float p = part[mt][r];
      p += __shfl_xor(p, 1, 64); p += __shfl_xor(p, 2, 64);
      p += __shfl_xor(p, 4, 64); p += __shfl_xor(p, 8, 64);
      part[mt][r] = p;
    }
  if (ml == 0)
#pragma unroll
    for (int mt=0; mt<4; ++mt)
#pragma unroll
      for (int r=0; r<4; ++r)
        sred[w][mt*16 + q*4 + r] = part[mt][r];
  __syncthreads();
  if (threadIdx.x < 64){
    const int t = threadIdx.x;
    float v = sred[0][t] + sred[1][t] + sred[2][t] + sred[3][t];
    outF[rowBase + t] = sigmoidf(v + scal[0]);
  }
}

// ---- MEGA: per-iteration fused edge pipeline (3 chained GEMMs, one LDS tile) ----
// GEMM1: h = relu(BE@W1c + P[src]+Q[recv]); GEMM2: b_e' = h@W2 + b2;
// !LAST: BE'=b_e' to HBM, GEMM3: score' = sigmoid(relu(b_e'@ea_w1+b1)@ea_w2+b2)
// LAST:  w_e = sigmoid(b_e'@ew_w+ew_b) directly (b_e' never stored).
template<bool LAST>
__global__ __launch_bounds__(256, 4)
void mega_k(u16* __restrict__ BE, const u16* __restrict__ w1cf,
            const u16* __restrict__ w2f, const u16* __restrict__ eaw1f,
            float* __restrict__ scoreOut, float* __restrict__ weOut,
            const u16* __restrict__ Pg, const u16* __restrict__ Qg,
            const int* __restrict__ srcI, const int* __restrict__ recvI,
            const float* __restrict__ b2,
            const float* __restrict__ sb1, const float* __restrict__ sv,
            const float* __restrict__ ssc,
            const float* __restrict__ wv, const float* __restrict__ wb)
{
  // one buffer, two lifetimes: frag-layout staged BE (32KB), then row-major-264
  // h / b_e' (33792B). Transitions guarded by barriers.
  __shared__ __align__(16) u16 sU[64*SHS];   // 33792B
  __shared__ float sred[4][64];
  __shared__ int sIdx[128];                  // src[0:64], recv[64:128]

  const int l  = threadIdx.x & 63;
  const int w  = threadIdx.x >> 6;
  const int q  = l >> 4;
  const int ml = l & 15;
  const long rowBase = (long)blockIdx.x * 64;

  // ---- stage BE tile once (frag layout) ----
  const u16* gA = BE + (size_t)(rowBase + w*16 + ml)*HD + q*8;
#pragma unroll
  for (int c=0; c<8; ++c) dma16(gA + c*32, sU + (c*4+w)*512);
  __syncthreads();

  // idx pre-stage: issued here, hidden under GEMM1; ordered by GEMM1-end barrier
  if (threadIdx.x < 128){
    const int t = threadIdx.x;
    sIdx[t] = (t < 64) ? srcI[rowBase + t] : recvI[rowBase + (t - 64)];
  }

  ffrag acc[4][4];
#pragma unroll
  for (int mt=0; mt<4; ++mt)
#pragma unroll
    for (int n=0; n<4; ++n) acc[mt][n] = (ffrag){0.f,0.f,0.f,0.f};

  // ---- GEMM1 (barrier-free): A = sU frag, B = w1cf global ----
  __builtin_amdgcn_s_setprio(1);
#pragma unroll 1
  for (int c=0; c<8; ++c){
    bfrag a[4], b[4];
#pragma unroll
    for (int n=0; n<4; ++n)
      b[n] = *(const bfrag*)(w1cf + (((size_t)c*16 + w*4 + n)*64 + l)*8);
#pragma unroll
    for (int mt=0; mt<4; ++mt) a[mt] = *(const bfrag*)(sU + (c*4+mt)*512 + l*8);
#pragma unroll
    for (int mt=0; mt<4; ++mt)
#pragma unroll
      for (int n=0; n<4; ++n)
        acc[mt][n] = __builtin_amdgcn_mfma_f32_16x16x32_bf16(a[mt], b[n], acc[mt][n], 0, 0, 0);
  }
  __builtin_amdgcn_s_setprio(0);
  __syncthreads();   // all sU(frag) reads done before overwrite

  // ---- epilogue1: h = relu(acc + P[src] + Q[recv]) -> sU row-major-264 ----
#pragma unroll
  for (int mt=0; mt<4; ++mt)
#pragma unroll
    for (int r=0; r<4; ++r){
      const int rl = mt*16 + q*4 + r;
      const int si = sIdx[rl];
      const int ri = sIdx[64 + rl];
      uint2 pu = *(const uint2*)(Pg + (size_t)si*HD + w*64 + ml*4);
      uint2 qu = *(const uint2*)(Qg + (size_t)ri*HD + w*64 + ml*4);
      u16 o[4];
      float pv[4] = { bf2f((u16)(pu.x & 0xffff)), bf2f((u16)(pu.x >> 16)),
                      bf2f((u16)(pu.y & 0xffff)), bf2f((u16)(pu.y >> 16)) };
      float qv[4] = { bf2f((u16)(qu.x & 0xffff)), bf2f((u16)(qu.x >> 16)),
                      bf2f((u16)(qu.y & 0xffff)), bf2f((u16)(qu.y >> 16)) };
#pragma unroll
      for (int n=0; n<4; ++n)
        o[n] = f2bf(fmaxf(acc[mt][n][r] + pv[n] + qv[n], 0.f));
      uint2 pk; pk.x = (u32)o[0] | ((u32)o[1]<<16); pk.y = (u32)o[2] | ((u32)o[3]<<16);
      *(uint2*)(sU + (size_t)rl*SHS + w*64 + ml*4) = pk;
    }
  __syncthreads();

  // ---- GEMM2 (barrier-free): A = sU row-major, B = w2f global ----
#pragma unroll
  for (int mt=0; mt<4; ++mt)
#pragma unroll
    for (int n=0; n<4; ++n) acc[mt][n] = (ffrag){0.f,0.f,0.f,0.f};
  __builtin_amdgcn_s_setprio(1);
#pragma unroll 1
  for (int c=0; c<8; ++c){
    bfrag a[4], b[4];
#pragma unroll
    for (int n=0; n<4; ++n)
      b[n] = *(const bfrag*)(w2f + (((size_t)c*16 + w*4 + n)*64 + l)*8);
#pragma unroll
    for (int mt=0; mt<4; ++mt)
      a[mt] = *(const bfrag*)(sU + (size_t)(mt*16+ml)*SHS + c*32 + q*8);
#pragma unroll
    for (int mt=0; mt<4; ++mt)
#pragma unroll
      for (int n=0; n<4; ++n)
        acc[mt][n] = __builtin_amdgcn_mfma_f32_16x16x32_bf16(a[mt], b[n], acc[mt][n], 0, 0, 0);
  }
  __builtin_amdgcn_s_setprio(0);

  float bia2[4];
#pragma unroll
  for (int n=0; n<4; ++n) bia2[n] = b2[(w*4+n)*16+ml];

  if constexpr (!LAST){
    __syncthreads();   // all sU reads of GEMM2 done before overwrite
    // epilogue2: b_e' -> global BE (in-place) + sU row-major for GEMM3
#pragma unroll
    for (int mt=0; mt<4; ++mt)
#pragma unroll
      for (int r=0; r<4; ++r){
        long row = rowBase + mt*16 + q*4 + r;
        u16 o[4];
#pragma unroll
        for (int n=0; n<4; ++n) o[n] = f2bf(acc[mt][n][r] + bia2[n]);
        uint2 pk; pk.x = (u32)o[0] | ((u32)o[1]<<16); pk.y = (u32)o[2] | ((u32)o[3]<<16);
        *(uint2*)(BE + (size_t)row*HD + w*64 + ml*4) = pk;
        *(uint2*)(sU + (size_t)(mt*16 + q*4 + r)*SHS + w*64 + ml*4) = pk;
      }
    __syncthreads();

    // ---- GEMM3 (barrier-free): A = sU row-major, B = eaw1f global ----
#pragma unroll
    for (int mt=0; mt<4; ++mt)
#pragma unroll
      for (int n=0; n<4; ++n) acc[mt][n] = (ffrag){0.f,0.f,0.f,0.f};
    __builtin_amdgcn_s_setprio(1);
#pragma unroll 1
    for (int c=0; c<8; ++c){
      bfrag a[4], b[4];
#pragma unroll
      for (int n=0; n<4; ++n)
        b[n] = *(const bfrag*)(eaw1f + (((size_t)c*16 + w*4 + n)*64 + l)*8);
#pragma unroll
      for (int mt=0; mt<4; ++mt)
        a[mt] = *(const bfrag*)(sU + (size_t)(mt*16+ml)*SHS + c*32 + q*8);
#pragma unroll
      for (int mt=0; mt<4; ++mt)
#pragma unroll
        for (int n=0; n<4; ++n)
          acc[mt][n] = __builtin_amdgcn_mfma_f32_16x16x32_bf16(a[mt], b[n], acc[mt][n], 0, 0, 0);
    }
    __builtin_amdgcn_s_setprio(0);
    float part[4][4];
#pragma unroll
    for (int mt=0; mt<4; ++mt)
#pragma unroll
      for (int r=0; r<4; ++r) part[mt][r] = 0.f;
#pragma unroll
    for (int n=0; n<4; ++n){
      const int col = (w*4+n)*16+ml;
      const float bb = sb1[col], vvn = sv[col];
#pragma unroll
      for (int mt=0; mt<4; ++mt)
#pragma unroll
        for (int r=0; r<4; ++r)
          part[mt][r] += fmaxf(acc[mt][n][r] + bb, 0.f) * vvn;
    }
#pragma unroll
    for (int mt=0; mt<4; ++mt)
#pragma unroll
      for (int r=0; r<4; ++r){
        float p = part[mt][r];
        p += __shfl_xor(p, 1, 64); p += __shfl_xor(p, 2, 64);
        p += __shfl_xor(p, 4, 64); p += __shfl_xor(p, 8, 64);
        part[mt][r] = p;
      }
    if (ml == 0)
#pragma unroll
      for (int mt=0; mt<4; ++mt)
#pragma unroll
        for (int r=0; r<4; ++r)
          sred[w][mt*16 + q*4 + r] = part[mt][r];
    __syncthreads();
    if (threadIdx.x < 64){
      const int t = threadIdx.x;
      float v = sred[0][t] + sred[1][t] + sred[2][t] + sred[3][t];
      scoreOut[rowBase + t] = sigmoidf(v + ssc[0]);
    }
  } else {
    // last iter: w_e = sigmoid(b_e' . ew_w + ew_b)
    float part[4][4];
#pragma unroll
    for (int mt=0; mt<4; ++mt)
#pragma unroll
      for (int r=0; r<4; ++r) part[mt][r] = 0.f;
#pragma unroll
    for (int n=0; n<4; ++n){
      const float vvn = wv[(w*4+n)*16+ml];
#pragma unroll
      for (int mt=0; mt<4; ++mt)
#pragma unroll
        for (int r=0; r<4; ++r)
          part[mt][r] += (acc[mt][n][r] + bia2[n]) * vvn;
    }
#pragma unroll
    for (int mt=0; mt<4; ++mt)
#pragma unroll
      for (int r=0; r<4; ++r){
        float p = part[mt][r];
        p += __shfl_xor(p, 1, 64); p += __shfl_xor(p, 2, 64);
        p += __shfl_xor(p, 4, 64); p += __shfl_xor(p, 8, 64);
        part[mt][r] = p;
      }
    if (ml == 0)
#pragma unroll
      for (int mt=0; mt<4; ++mt)
#pragma unroll
        for (int r=0; r<4; ++r)
          sred[w][mt*16 + q*4 + r] = part[mt][r];
    __syncthreads();
    if (threadIdx.x < 64){
      const int t = threadIdx.x;
      float v = sred[0][t] + sred[1][t] + sred[2][t] + sred[3][t];
      weOut[rowBase + t] = sigmoidf(v + wb[0]);
    }
  }
}

// repack B[256 x 256] f32 row-major -> bf16 frag layout [c][n][lane][8],
// K-rows permuted: packed row kp takes source feature inv(kp).
__global__ void repack_k(const float* __restrict__ B, u16* __restrict__ out){
  int t = blockIdx.x*256 + threadIdx.x;        // 8192 total
  int l = t & 63, n = (t>>6)&15, c = t>>10;
  int col = n*16 + (l&15);
  int kbase = c*32 + ((l>>4)<<3);
#pragma unroll
  for (int j=0; j<8; ++j){
    int kp = kbase + j;
    int f = (kp>>6)*64 + (kp&3)*16 + ((kp>>2)&15);   // inv(kp)
    out[(size_t)t*8 + j] = f2bf(B[(size_t)f*HD + col]);
  }
}

__global__ void flags_k(const int* __restrict__ batch, const int* __restrict__ heads,
                        const int* __restrict__ tails, float* __restrict__ flags){
  int n = blockIdx.x*256 + threadIdx.x;
  int g = batch[n];
  flags[2*n]   = (n == heads[g]) ? 1.f : 0.f;
  flags[2*n+1] = (n == tails[g]) ? 1.f : 0.f;
}

// exclusive prefix sum of degrees -> CSR offsets (+ cursor copy), single block
__global__ void scan_k(const int* __restrict__ deg, int* __restrict__ offs,
                       int* __restrict__ cur){
  __shared__ int part[256];
  int tid = threadIdx.x;
  int base = tid * 64;
  int s = 0;
  for (int j=0; j<64; ++j) s += deg[base+j];
  part[tid] = s;
  __syncthreads();
  if (tid == 0){
    int run = 0;
    for (int i=0; i<256; ++i){ int t = part[i]; part[i] = run; run += t; }
  }
  __syncthreads();
  int run = part[tid];
  for (int j=0; j<64; ++j){
    offs[base+j] = run; cur[base+j] = run; run += deg[base+j];
  }
  if (tid == 255) offs[NN] = run;
}

__global__ void fill_k(const int* __restrict__ recv, int* __restrict__ cur,
                       int* __restrict__ eids){
  int e = blockIdx.x*256 + threadIdx.x;
  int r = recv[e];
  int p = atomicAdd(&cur[r], 1);
  eids[p] = e;
}

// per-node softmax over incoming edges + weighted aggregation, one wave per node
__global__ __launch_bounds__(256)
void agg_k(const float* __restrict__ score, const u16* __restrict__ BE,
           const int* __restrict__ offs, const int* __restrict__ eids,
           float* __restrict__ bv, u16* __restrict__ bvb){
  int node = blockIdx.x*4 + (threadIdx.x >> 6);
  int l = threadIdx.x & 63;
  int beg = offs[node], end = offs[node+1];

  float m = -1e30f;
  for (int i=beg+l; i<end; i+=64) m = fmaxf(m, score[eids[i]]);
#pragma unroll
  for (int d=1; d<64; d<<=1) m = fmaxf(m, __shfl_xor(m, d, 64));

  float s = 0.f;
  for (int i=beg+l; i<end; i+=64) s += __expf(score[eids[i]] - m);
#pragma unroll
  for (int d=1; d<64; d<<=1) s += __shfl_xor(s, d, 64);

  float deg = (float)(end - beg);
  float scale = (end > beg) ? (1.f/s) * (1.f/(1.f+deg)) : 0.f;

  float a0=0.f, a1=0.f, a2=0.f, a3=0.f;
  for (int i=beg; i<end; ++i){
    int e = eids[i];
    float al = __expf(score[e] - m);
    uint2 uv = *(const uint2*)(BE + (size_t)e*HD + l*4);
    a0 += al * bf2f((u16)(uv.x & 0xffff));
    a1 += al * bf2f((u16)(uv.x >> 16));
    a2 += al * bf2f((u16)(uv.y & 0xffff));
    a3 += al * bf2f((u16)(uv.y >> 16));
  }
  size_t o = (size_t)node*HD + l*4;
  a0 *= scale; a1 *= scale; a2 *= scale; a3 *= scale;
  bv[o+0]=a0; bv[o+1]=a1; bv[o+2]=a2; bv[o+3]=a3;
  uint2 p; p.x = (u32)f2bf(a0) | ((u32)f2bf(a1)<<16);
  p.y = (u32)f2bf(a2) | ((u32)f2bf(a3)<<16);
  *(uint2*)(bvb + o) = p;
}

// graph head: g_max + gather head/tail rows -> g_G [64][768] f32 (position space)
__global__ void gmax_k(const float* __restrict__ bv, const int* __restrict__ heads,
                       const int* __restrict__ tails, float* __restrict__ gG){
  int g = blockIdx.x, col = threadIdx.x;
  float mx = -1e30f;
  const float* p = bv + (size_t)g*256*HD + col;
  for (int i=0; i<256; ++i) mx = fmaxf(mx, p[(size_t)i*HD]);
  gG[g*768 + col]       = mx;
  gG[g*768 + 256 + col] = bv[(size_t)heads[g]*HD + col];
  gG[g*768 + 512 + col] = bv[(size_t)tails[g]*HD + col];
}

__global__ void glog_k(const float* __restrict__ gG, const float* __restrict__ w1,
                       const float* __restrict__ b1, const float* __restrict__ w2,
                       const float* __restrict__ b2, float* __restrict__ logits){
  int g = blockIdx.x, n = threadIdx.x;
  float a = b1[n];
  const float* gg = gG + g*768;
  for (int k=0; k<768; ++k){
    int b = k >> 8, p = k & 255;
    int f = (p>>6)*64 + (p&3)*16 + ((p>>2)&15);   // inv(p)
    a += gg[k] * w1[(size_t)(b*256 + f)*HD + n];
  }
  a = fmaxf(a, 0.f) * w2[n];
#pragma unroll
  for (int d=1; d<64; d<<=1) a += __shfl_xor(a, d, 64);
  __shared__ float red[4];
  if ((threadIdx.x & 63) == 0) red[threadIdx.x >> 6] = a;
  __syncthreads();
  if (threadIdx.x == 0) logits[g] = red[0]+red[1]+red[2]+red[3] + b2[0];
}

__global__ void gfin_k(const float* __restrict__ gG, const float* __restrict__ logits,
                       float* __restrict__ out){
  int tid = threadIdx.x;
  float m = -1e30f;
  for (int g=0; g<NG; ++g) m = fmaxf(m, logits[g]);
  float s = 0.f;
  for (int g=0; g<NG; ++g) s += __expf(logits[g] - m);
  float inv = 1.f/s;
  for (int j=tid; j<768; j+=256){
    int b = j >> 8, f = j & 255;
    int p = (f>>6)*64 + (f&15)*4 + ((f>>4)&3);    // pi(f): un-permute for output
    float o = 0.f;
    for (int g=0; g<NG; ++g) o += __expf(logits[g]-m)*inv * gG[g*768 + b*256 + p];
    out[j] = o;
  }
}

extern "C" void kernel_launch(void* const* d_in, const int* in_sizes, int n_in,
                              void* d_out, int out_size, void* d_ws, size_t ws_size,
                              hipStream_t stream)
{
  const float* ef    = (const float*)d_in[0];
  const float* gall  = (const float*)d_in[1];
  const float* ea_w1 = (const float*)d_in[2];
  const float* ea_b1 = (const float*)d_in[3];
  const float* ea_w2 = (const float*)d_in[4];
  const float* ea_b2 = (const float*)d_in[5];
  const float* eu_w1 = (const float*)d_in[6];
  const float* eu_b1 = (const float*)d_in[7];
  const float* eu_w2 = (const float*)d_in[8];
  const float* eu_b2 = (const float*)d_in[9];
  const float* gw_w1 = (const float*)d_in[10];
  const float* gw_b1 = (const float*)d_in[11];
  const float* gw_w2 = (const float*)d_in[12];
  const float* gw_b2 = (const float*)d_in[13];
  const float* ew_w  = (const float*)d_in[14];
  const float* ew_b  = (const float*)d_in[15];
  const int* eidx    = (const int*)d_in[16];
  const int* srcI    = eidx;
  const int* recvI   = eidx + NE;
  const int* ndeg    = (const int*)d_in[17];
  const int* batch   = (const int*)d_in[18];
  const int* heads   = (const int*)d_in[19];
  const int* tails   = (const int*)d_in[20];
  float* out = (float*)d_out;

  char* wsb = (char*)d_ws;
  size_t off = 0;
  auto alloc = [&](size_t sz)->char*{
    char* p = wsb + off; off = (off + sz + 255) & ~(size_t)255; return p;
  };
  u16*   BE    = (u16*)  alloc((size_t)NE*HD*2);
  float* score = (float*)alloc((size_t)NE*4);
  u16*   P     = (u16*)  alloc((size_t)NN*HD*2);
  u16*   Q     = (u16*)  alloc((size_t)NN*HD*2);
  float* bv    = (float*)alloc((size_t)NN*HD*4);
  u16*   bvb   = (u16*)  alloc((size_t)NN*HD*2);
  int*   offs  = (int*)  alloc((size_t)(NN+1)*4);
  int*   cur   = (int*)  alloc((size_t)NN*4);
  int*   eids  = (int*)  alloc((size_t)NE*4);
  float* flags = (float*)alloc((size_t)NN*8);
  u16*   eaw1f = (u16*)  alloc((size_t)65536*2);
  u16*   w1af  = (u16*)  alloc((size_t)65536*2);
  u16*   w1bf  = (u16*)  alloc((size_t)65536*2);
  u16*   w1cf  = (u16*)  alloc((size_t)65536*2);
  u16*   euw2f = (u16*)  alloc((size_t)65536*2);
  float* gG    = (float*)alloc((size_t)NG*768*4);
  float* logits= (float*)alloc((size_t)NG*4);

  // one-time per launch: weight repacks + flags + CSR
  repack_k<<<32,256,0,stream>>>(ea_w1, eaw1f);
  repack_k<<<32,256,0,stream>>>(eu_w1, w1af);              // rows 0..255   (src b_v part)
  repack_k<<<32,256,0,stream>>>(eu_w1 + 258*HD, w1bf);     // rows 258..513 (recv b_v part)
  repack_k<<<32,256,0,stream>>>(eu_w1 + 516*HD, w1cf);     // rows 516..771 (b_e part)
  repack_k<<<32,256,0,stream>>>(eu_w2, euw2f);
  flags_k<<<NN/256,256,0,stream>>>(batch, heads, tails, flags);
  scan_k<<<1,256,0,stream>>>(ndeg, offs, cur);
  fill_k<<<NE/256,256,0,stream>>>(recvI, cur, eids);

  // fused: b_e init (BE to HBM) + iter0 score, one pass over ef
  ibs_k<<<NE/64,256,0,stream>>>(ef, gall, BE, eaw1f, score, ea_b1, ea_w2, ea_b2);

  for (int it=0; it<3; ++it){
    // scatter-softmax + degree-normalized aggregation -> b_v (f32 + bf16)
    agg_k<<<NN/4,256,0,stream>>>(score, BE, offs, eids, bv, bvb);
    // P = r_v@W1a + b1 ; Q = r_v@W1b (one dispatch, grid.y selects half)
    gemm_k<MODE_PQ><<<dim3(NN/64,2),256,0,stream>>>(bvb, w1af, w1bf, nullptr,
        P, Q, eu_b1, nullptr, nullptr, flags, eu_w1 + 256*HD, eu_w1 + 514*HD);
    // fused edge update (+ next score, or final w_e)
    if (it < 2){
      mega_k<false><<<NE/64,256,0,stream>>>(BE, w1cf, euw2f, eaw1f,
          score, nullptr, P, Q, srcI, recvI, eu_b2,
          ea_b1, ea_w2, ea_b2, nullptr, nullptr);
    } else {
      mega_k<true><<<NE/64,256,0,stream>>>(BE, w1cf, euw2f, eaw1f,
          nullptr, out, P, Q, srcI, recvI, eu_b2,
          nullptr, nullptr, nullptr, ew_w, ew_b);
    }
  }

  // graph head (f32 exact, tiny; un-permutes positions)
  gmax_k<<<NG,256,0,stream>>>(bv, heads, tails, gG);
  glog_k<<<NG,256,0,stream>>>(gG, gw_w1, gw_b1, gw_w2, gw_b2, logits);
  gfin_k<<<1,256,0,stream>>>(gG, logits, out + NE);
}

// Round 8
// 991.151 us; speedup vs baseline: 1.0490x; 1.0490x over previous
//
#include <hip/hip_runtime.h>
#include <stdint.h>

typedef unsigned short u16;
typedef unsigned int   u32;

#define NN 16384   // nodes
#define NE 262144  // edges
#define NG 64      // graphs
#define HD 256     // hidden
#define SHS 264    // row-major LDS tile stride in u16 (+8 pad -> 2-way-free banks)

typedef __attribute__((ext_vector_type(8))) short bfrag;  // 8 bf16 (4 VGPR)
typedef __attribute__((ext_vector_type(4))) float ffrag;  // 4 f32 acc

__device__ __forceinline__ float bf2f(u16 h){
  union { u32 u; float f; } v; v.u = ((u32)h) << 16; return v.f;
}
__device__ __forceinline__ u16 f2bf(float x){
  union { float f; u32 u; } v; v.f = x;
  u32 r = v.u + 0x7fffu + ((v.u >> 16) & 1u);
  return (u16)(r >> 16);
}
__device__ __forceinline__ float sigmoidf(float x){ return 1.f/(1.f+__expf(-x)); }

// async global->LDS DMA, 16B/lane: lane i lands at (wave-uniform base) + i*16
__device__ __forceinline__ void dma16(const void* g, void* l){
  __builtin_amdgcn_global_load_lds(
      (const __attribute__((address_space(1))) u32*)g,
      (__attribute__((address_space(3))) u32*)l, 16, 0, 0);
}

// Feature permutation pi: feature f lives at position p(f)=(f>>6)*64+(f&15)*4
// +((f>>4)&3); inv(p)=(p>>6)*64+(p&3)*16+((p>>2)&15). Weights repacked with
// K-rows permuted by inv(). Epilogues write packed uint2; P/Q gathers are one
// uint2 per row.
//
// R14 == R13 resubmitted verbatim (R7 bench was an infra failure: "container
// failed twice", no counters). R13 = exact R10 body (999us best) plus two
// local non-mega changes:
//  * agg_k single-pass: scores are sigmoid outputs in (0,1) so exp(score)
//    is in (1,e) -- the segment-max shift is an exact mathematical no-op.
//    Max pass AND sum pass deleted; s accumulates in the weighted loop.
//  * glog_k: 1024 threads, k-loop split 4 ways, LDS partial combine before
//    relu (64-block serial-768 loop was latency-bound on 1/4 of CUs).

enum { MODE_SCORE=0, MODE_PQ=4 };

// SCORE: outF = sigmoid(relu(A@Bf0+bias)@vec + scal)  (per-row scalar)
// PQ (grid.y=0/1): out{0,1} = A@Bf{0,1} [+bias] + flag-rank1(ht{0,1})
template<int MODE>
__global__ __launch_bounds__(256, 4)
void gemm_k(const u16* __restrict__ A, const u16* __restrict__ Bf0,
            const u16* __restrict__ Bf1,
            float* __restrict__ outF, u16* __restrict__ out0, u16* __restrict__ out1,
            const float* __restrict__ bias, const float* __restrict__ vec,
            const float* __restrict__ scal, const float* __restrict__ flags,
            const float* __restrict__ ht0, const float* __restrict__ ht1)
{
  __shared__ __align__(16) u16 sA[16384];   // 32KB, frag layout [(c*4+mt)*512 + l*8]
  __shared__ float sred[4][64];

  const int l  = threadIdx.x & 63;
  const int w  = threadIdx.x >> 6;
  const int q  = l >> 4;
  const int ml = l & 15;
  const long rowBase = (long)blockIdx.x * 64;

  const u16* Bf   = Bf0;
  u16*       outB = out0;
  const float* htp = ht0;
  const float* bp  = bias;
  if (MODE==MODE_PQ && blockIdx.y){ Bf = Bf1; outB = out1; htp = ht1; bp = nullptr; }

  // stage A tile once (frag layout); init-acc loads fly under the staging drain
  const u16* gA = A + (size_t)(rowBase + w*16 + ml)*HD + q*8;
#pragma unroll
  for (int c=0; c<8; ++c) dma16(gA + c*32, sA + (c*4+w)*512);

  ffrag acc[4][4];
  if constexpr (MODE==MODE_SCORE){
#pragma unroll
    for (int n=0; n<4; ++n){
      const float bb = bias[(w*4+n)*16+ml];
#pragma unroll
      for (int mt=0; mt<4; ++mt) acc[mt][n] = (ffrag){bb,bb,bb,bb};
    }
  } else {
    float h0[4], h1[4], bb[4];
#pragma unroll
    for (int n=0; n<4; ++n){
      const int col = (w*4+n)*16+ml;
      h0[n] = htp[col]; h1[n] = htp[HD+col]; bb[n] = bp ? bp[col] : 0.f;
    }
    float2 fl[16];
#pragma unroll
    for (int i=0; i<16; ++i){
      long row = rowBase + (i>>2)*16 + q*4 + (i&3);
      fl[i] = *(const float2*)(flags + 2*row);
    }
#pragma unroll
    for (int i=0; i<16; ++i){
      const int mt = i>>2, r = i&3;
      const float fh = fl[i].x, ft = fl[i].y;
#pragma unroll
      for (int n=0; n<4; ++n)
        acc[mt][n][r] = bb[n] + fh*h0[n] + ft*h1[n];
    }
  }
  __syncthreads();

  __builtin_amdgcn_s_setprio(1);
#pragma unroll 1
  for (int c=0; c<8; ++c){
    bfrag a[4], b[4];
#pragma unroll
    for (int n=0; n<4; ++n)
      b[n] = *(const bfrag*)(Bf + (((size_t)c*16 + w*4 + n)*64 + l)*8);
#pragma unroll
    for (int mt=0; mt<4; ++mt) a[mt] = *(const bfrag*)(sA + (c*4+mt)*512 + l*8);
#pragma unroll
    for (int mt=0; mt<4; ++mt)
#pragma unroll
      for (int n=0; n<4; ++n)
        acc[mt][n] = __builtin_amdgcn_mfma_f32_16x16x32_bf16(a[mt], b[n], acc[mt][n], 0, 0, 0);
  }
  __builtin_amdgcn_s_setprio(0);

  if constexpr (MODE==MODE_SCORE){
    float part[4][4];
#pragma unroll
    for (int mt=0; mt<4; ++mt)
#pragma unroll
      for (int r=0; r<4; ++r) part[mt][r] = 0.f;
#pragma unroll
    for (int n=0; n<4; ++n){
      const float vvn = vec[(w*4+n)*16+ml];
#pragma unroll
      for (int mt=0; mt<4; ++mt)
#pragma unroll
        for (int r=0; r<4; ++r)
          part[mt][r] += fmaxf(acc[mt][n][r], 0.f) * vvn;   // bias in acc-init
    }
#pragma unroll
    for (int mt=0; mt<4; ++mt)
#pragma unroll
      for (int r=0; r<4; ++r){
        float p = part[mt][r];
        p += __shfl_xor(p, 1, 64); p += __shfl_xor(p, 2, 64);
        p += __shfl_xor(p, 4, 64); p += __shfl_xor(p, 8, 64);
        part[mt][r] = p;
      }
    if (ml == 0)
#pragma unroll
      for (int mt=0; mt<4; ++mt)
#pragma unroll
        for (int r=0; r<4; ++r)
          sred[w][mt*16 + q*4 + r] = part[mt][r];
    __syncthreads();
    if (threadIdx.x < 64){
      const int t = threadIdx.x;
      float v = sred[0][t] + sred[1][t] + sred[2][t] + sred[3][t];
      outF[rowBase + t] = sigmoidf(v + scal[0]);
    }
  } else { // MODE_PQ: all additive terms already in acc-init
#pragma unroll
    for (int mt=0; mt<4; ++mt)
#pragma unroll
      for (int r=0; r<4; ++r){
        long row = rowBase + mt*16 + q*4 + r;
        u16 o[4];
#pragma unroll
        for (int n=0; n<4; ++n) o[n] = f2bf(acc[mt][n][r]);
        uint2 pk; pk.x = (u32)o[0] | ((u32)o[1]<<16); pk.y = (u32)o[2] | ((u32)o[3]<<16);
        *(uint2*)(outB + (size_t)row*HD + w*64 + ml*4) = pk;
      }
  }
}

// ---- MEGA: per-iteration fused edge pipeline (3 chained GEMMs, one LDS tile) ----
// GEMM1: h = relu(BE@W1c + P[src]+Q[recv]); GEMM2: b_e' = h@W2 + b2;
// !LAST: BE'=b_e' to HBM, GEMM3: score' = sigmoid(relu(b_e'@ea_w1+b1)@ea_w2+b2)
// LAST:  w_e = sigmoid(b_e'@ew_w+ew_b) directly (b_e' never stored).
template<bool LAST>
__global__ __launch_bounds__(256, 4)
void mega_k(u16* __restrict__ BE, const u16* __restrict__ w1cf,
            const u16* __restrict__ w2f, const u16* __restrict__ eaw1f,
            float* __restrict__ scoreOut, float* __restrict__ weOut,
            const u16* __restrict__ Pg, const u16* __restrict__ Qg,
            const int* __restrict__ srcI, const int* __restrict__ recvI,
            const float* __restrict__ b2,
            const float* __restrict__ sb1, const float* __restrict__ sv,
            const float* __restrict__ ssc,
            const float* __restrict__ wv, const float* __restrict__ wb)
{
  // one buffer, two lifetimes: frag-layout staged BE (32KB), then row-major-264
  // h / b_e' (33792B). Transitions guarded by barriers.
  __shared__ __align__(16) u16 sU[64*SHS];   // 33792B
  __shared__ float sred[4][64];
  __shared__ int sIdx[128];                  // src[0:64], recv[64:128]

  const int l  = threadIdx.x & 63;
  const int w  = threadIdx.x >> 6;
  const int q  = l >> 4;
  const int ml = l & 15;
  const long rowBase = (long)blockIdx.x * 64;

  // ---- stage BE tile once (frag layout) ----
  const u16* gA = BE + (size_t)(rowBase + w*16 + ml)*HD + q*8;
#pragma unroll
  for (int c=0; c<8; ++c) dma16(gA + c*32, sU + (c*4+w)*512);
  __syncthreads();

  // idx pre-stage: issued here, hidden under GEMM1; ordered by GEMM1-end barrier
  if (threadIdx.x < 128){
    const int t = threadIdx.x;
    sIdx[t] = (t < 64) ? srcI[rowBase + t] : recvI[rowBase + (t - 64)];
  }

  ffrag acc[4][4];
#pragma unroll
  for (int mt=0; mt<4; ++mt)
#pragma unroll
    for (int n=0; n<4; ++n) acc[mt][n] = (ffrag){0.f,0.f,0.f,0.f};

  // ---- GEMM1 (barrier-free): A = sU frag, B = w1cf global ----
  __builtin_amdgcn_s_setprio(1);
#pragma unroll 1
  for (int c=0; c<8; ++c){
    bfrag a[4], b[4];
#pragma unroll
    for (int n=0; n<4; ++n)
      b[n] = *(const bfrag*)(w1cf + (((size_t)c*16 + w*4 + n)*64 + l)*8);
#pragma unroll
    for (int mt=0; mt<4; ++mt) a[mt] = *(const bfrag*)(sU + (c*4+mt)*512 + l*8);
#pragma unroll
    for (int mt=0; mt<4; ++mt)
#pragma unroll
      for (int n=0; n<4; ++n)
        acc[mt][n] = __builtin_amdgcn_mfma_f32_16x16x32_bf16(a[mt], b[n], acc[mt][n], 0, 0, 0);
  }
  __builtin_amdgcn_s_setprio(0);
  __syncthreads();   // all sU(frag) reads done before overwrite

  // ---- epilogue1: h = relu(acc + P[src] + Q[recv]) -> sU row-major-264 ----
#pragma unroll
  for (int mt=0; mt<4; ++mt)
#pragma unroll
    for (int r=0; r<4; ++r){
      const int rl = mt*16 + q*4 + r;
      const int si = sIdx[rl];
      const int ri = sIdx[64 + rl];
      uint2 pu = *(const uint2*)(Pg + (size_t)si*HD + w*64 + ml*4);
      uint2 qu = *(const uint2*)(Qg + (size_t)ri*HD + w*64 + ml*4);
      u16 o[4];
      float pv[4] = { bf2f((u16)(pu.x & 0xffff)), bf2f((u16)(pu.x >> 16)),
                      bf2f((u16)(pu.y & 0xffff)), bf2f((u16)(pu.y >> 16)) };
      float qv[4] = { bf2f((u16)(qu.x & 0xffff)), bf2f((u16)(qu.x >> 16)),
                      bf2f((u16)(qu.y & 0xffff)), bf2f((u16)(qu.y >> 16)) };
#pragma unroll
      for (int n=0; n<4; ++n)
        o[n] = f2bf(fmaxf(acc[mt][n][r] + pv[n] + qv[n], 0.f));
      uint2 pk; pk.x = (u32)o[0] | ((u32)o[1]<<16); pk.y = (u32)o[2] | ((u32)o[3]<<16);
      *(uint2*)(sU + (size_t)rl*SHS + w*64 + ml*4) = pk;
    }
  __syncthreads();

  // ---- GEMM2 (barrier-free): A = sU row-major, B = w2f global ----
#pragma unroll
  for (int mt=0; mt<4; ++mt)
#pragma unroll
    for (int n=0; n<4; ++n) acc[mt][n] = (ffrag){0.f,0.f,0.f,0.f};
  __builtin_amdgcn_s_setprio(1);
#pragma unroll 1
  for (int c=0; c<8; ++c){
    bfrag a[4], b[4];
#pragma unroll
    for (int n=0; n<4; ++n)
      b[n] = *(const bfrag*)(w2f + (((size_t)c*16 + w*4 + n)*64 + l)*8);
#pragma unroll
    for (int mt=0; mt<4; ++mt)
      a[mt] = *(const bfrag*)(sU + (size_t)(mt*16+ml)*SHS + c*32 + q*8);
#pragma unroll
    for (int mt=0; mt<4; ++mt)
#pragma unroll
      for (int n=0; n<4; ++n)
        acc[mt][n] = __builtin_amdgcn_mfma_f32_16x16x32_bf16(a[mt], b[n], acc[mt][n], 0, 0, 0);
  }
  __builtin_amdgcn_s_setprio(0);

  float bia2[4];
#pragma unroll
  for (int n=0; n<4; ++n) bia2[n] = b2[(w*4+n)*16+ml];

  if constexpr (!LAST){
    __syncthreads();   // all sU reads of GEMM2 done before overwrite
    // epilogue2: b_e' -> global BE (in-place) + sU row-major for GEMM3
#pragma unroll
    for (int mt=0; mt<4; ++mt)
#pragma unroll
      for (int r=0; r<4; ++r){
        long row = rowBase + mt*16 + q*4 + r;
        u16 o[4];
#pragma unroll
        for (int n=0; n<4; ++n) o[n] = f2bf(acc[mt][n][r] + bia2[n]);
        uint2 pk; pk.x = (u32)o[0] | ((u32)o[1]<<16); pk.y = (u32)o[2] | ((u32)o[3]<<16);
        *(uint2*)(BE + (size_t)row*HD + w*64 + ml*4) = pk;
        *(uint2*)(sU + (size_t)(mt*16 + q*4 + r)*SHS + w*64 + ml*4) = pk;
      }
    __syncthreads();

    // ---- GEMM3 (barrier-free): A = sU row-major, B = eaw1f global ----
#pragma unroll
    for (int mt=0; mt<4; ++mt)
#pragma unroll
      for (int n=0; n<4; ++n) acc[mt][n] = (ffrag){0.f,0.f,0.f,0.f};
    __builtin_amdgcn_s_setprio(1);
#pragma unroll 1
    for (int c=0; c<8; ++c){
      bfrag a[4], b[4];
#pragma unroll
      for (int n=0; n<4; ++n)
        b[n] = *(const bfrag*)(eaw1f + (((size_t)c*16 + w*4 + n)*64 + l)*8);
#pragma unroll
      for (int mt=0; mt<4; ++mt)
        a[mt] = *(const bfrag*)(sU + (size_t)(mt*16+ml)*SHS + c*32 + q*8);
#pragma unroll
      for (int mt=0; mt<4; ++mt)
#pragma unroll
        for (int n=0; n<4; ++n)
          acc[mt][n] = __builtin_amdgcn_mfma_f32_16x16x32_bf16(a[mt], b[n], acc[mt][n], 0, 0, 0);
    }
    __builtin_amdgcn_s_setprio(0);
    float part[4][4];
#pragma unroll
    for (int mt=0; mt<4; ++mt)
#pragma unroll
      for (int r=0; r<4; ++r) part[mt][r] = 0.f;
#pragma unroll
    for (int n=0; n<4; ++n){
      const int col = (w*4+n)*16+ml;
      const float bb = sb1[col], vvn = sv[col];
#pragma unroll
      for (int mt=0; mt<4; ++mt)
#pragma unroll
        for (int r=0; r<4; ++r)
          part[mt][r] += fmaxf(acc[mt][n][r] + bb, 0.f) * vvn;
    }
#pragma unroll
    for (int mt=0; mt<4; ++mt)
#pragma unroll
      for (int r=0; r<4; ++r){
        float p = part[mt][r];
        p += __shfl_xor(p, 1, 64); p += __shfl_xor(p, 2, 64);
        p += __shfl_xor(p, 4, 64); p += __shfl_xor(p, 8, 64);
        part[mt][r] = p;
      }
    if (ml == 0)
#pragma unroll
      for (int mt=0; mt<4; ++mt)
#pragma unroll
        for (int r=0; r<4; ++r)
          sred[w][mt*16 + q*4 + r] = part[mt][r];
    __syncthreads();
    if (threadIdx.x < 64){
      const int t = threadIdx.x;
      float v = sred[0][t] + sred[1][t] + sred[2][t] + sred[3][t];
      scoreOut[rowBase + t] = sigmoidf(v + ssc[0]);
    }
  } else {
    // last iter: w_e = sigmoid(b_e' . ew_w + ew_b)
    float part[4][4];
#pragma unroll
    for (int mt=0; mt<4; ++mt)
#pragma unroll
      for (int r=0; r<4; ++r) part[mt][r] = 0.f;
#pragma unroll
    for (int n=0; n<4; ++n){
      const float vvn = wv[(w*4+n)*16+ml];
#pragma unroll
      for (int mt=0; mt<4; ++mt)
#pragma unroll
        for (int r=0; r<4; ++r)
          part[mt][r] += (acc[mt][n][r] + bia2[n]) * vvn;
    }
#pragma unroll
    for (int mt=0; mt<4; ++mt)
#pragma unroll
      for (int r=0; r<4; ++r){
        float p = part[mt][r];
        p += __shfl_xor(p, 1, 64); p += __shfl_xor(p, 2, 64);
        p += __shfl_xor(p, 4, 64); p += __shfl_xor(p, 8, 64);
        part[mt][r] = p;
      }
    if (ml == 0)
#pragma unroll
      for (int mt=0; mt<4; ++mt)
#pragma unroll
        for (int r=0; r<4; ++r)
          sred[w][mt*16 + q*4 + r] = part[mt][r];
    __syncthreads();
    if (threadIdx.x < 64){
      const int t = threadIdx.x;
      float v = sred[0][t] + sred[1][t] + sred[2][t] + sred[3][t];
      weOut[rowBase + t] = sigmoidf(v + wb[0]);
    }
  }
}

// repack B[256 x 256] f32 row-major -> bf16 frag layout [c][n][lane][8],
// K-rows permuted: packed row kp takes source feature inv(kp).
__global__ void repack_k(const float* __restrict__ B, u16* __restrict__ out){
  int t = blockIdx.x*256 + threadIdx.x;        // 8192 total
  int l = t & 63, n = (t>>6)&15, c = t>>10;
  int col = n*16 + (l&15);
  int kbase = c*32 + ((l>>4)<<3);
#pragma unroll
  for (int j=0; j<8; ++j){
    int kp = kbase + j;
    int f = (kp>>6)*64 + (kp&3)*16 + ((kp>>2)&15);   // inv(kp)
    out[(size_t)t*8 + j] = f2bf(B[(size_t)f*HD + col]);
  }
}

// b_e(iter0) = [edge_features | g_all] -> bf16, position-permuted layout
__global__ void initbe_k(const float* __restrict__ ef, const float* __restrict__ gall,
                         u16* __restrict__ BE){
  int t = blockIdx.x*256 + threadIdx.x;        // NE*64
  int e = t >> 6; int p4 = (t & 63) * 4;
  int w64 = p4 >> 6, mlr = (p4 >> 2) & 15;
  u16 o[4];
#pragma unroll
  for (int i=0; i<4; ++i){
    int f = w64*64 + i*16 + mlr;                 // inv(p4+i)
    float v = (f < 192) ? ef[(size_t)e*192 + f] : gall[f - 192];
    o[i] = f2bf(v);
  }
  uint2 pk; pk.x = (u32)o[0] | ((u32)o[1]<<16); pk.y = (u32)o[2] | ((u32)o[3]<<16);
  *(uint2*)(BE + (size_t)e*HD + p4) = pk;
}

__global__ void flags_k(const int* __restrict__ batch, const int* __restrict__ heads,
                        const int* __restrict__ tails, float* __restrict__ flags){
  int n = blockIdx.x*256 + threadIdx.x;
  int g = batch[n];
  flags[2*n]   = (n == heads[g]) ? 1.f : 0.f;
  flags[2*n+1] = (n == tails[g]) ? 1.f : 0.f;
}

// exclusive prefix sum of degrees -> CSR offsets (+ cursor copy), single block
__global__ void scan_k(const int* __restrict__ deg, int* __restrict__ offs,
                       int* __restrict__ cur){
  __shared__ int part[256];
  int tid = threadIdx.x;
  int base = tid * 64;
  int s = 0;
  for (int j=0; j<64; ++j) s += deg[base+j];
  part[tid] = s;
  __syncthreads();
  if (tid == 0){
    int run = 0;
    for (int i=0; i<256; ++i){ int t = part[i]; part[i] = run; run += t; }
  }
  __syncthreads();
  int run = part[tid];
  for (int j=0; j<64; ++j){
    offs[base+j] = run; cur[base+j] = run; run += deg[base+j];
  }
  if (tid == 255) offs[NN] = run;
}

__global__ void fill_k(const int* __restrict__ recv, int* __restrict__ cur,
                       int* __restrict__ eids){
  int e = blockIdx.x*256 + threadIdx.x;
  int r = recv[e];
  int p = atomicAdd(&cur[r], 1);
  eids[p] = e;
}

// per-node softmax over incoming edges + weighted aggregation, one wave per node.
// Single pass: scores are sigmoid outputs in (0,1) => exp(score) in (1,e);
// the segment-max shift is an exact no-op, and the denominator accumulates
// alongside the numerator (all lanes hold the same al).
__global__ __launch_bounds__(256)
void agg_k(const float* __restrict__ score, const u16* __restrict__ BE,
           const int* __restrict__ offs, const int* __restrict__ eids,
           float* __restrict__ bv, u16* __restrict__ bvb){
  int node = blockIdx.x*4 + (threadIdx.x >> 6);
  int l = threadIdx.x & 63;
  int beg = offs[node], end = offs[node+1];

  float s = 0.f;
  float a0=0.f, a1=0.f, a2=0.f, a3=0.f;
  for (int i=beg; i<end; ++i){
    int e = eids[i];
    float al = __expf(score[e]);
    uint2 uv = *(const uint2*)(BE + (size_t)e*HD + l*4);
    s  += al;
    a0 += al * bf2f((u16)(uv.x & 0xffff));
    a1 += al * bf2f((u16)(uv.x >> 16));
    a2 += al * bf2f((u16)(uv.y & 0xffff));
    a3 += al * bf2f((u16)(uv.y >> 16));
  }
  float deg = (float)(end - beg);
  float scale = (end > beg) ? (1.f/s) * (1.f/(1.f+deg)) : 0.f;

  size_t o = (size_t)node*HD + l*4;
  a0 *= scale; a1 *= scale; a2 *= scale; a3 *= scale;
  bv[o+0]=a0; bv[o+1]=a1; bv[o+2]=a2; bv[o+3]=a3;
  uint2 p; p.x = (u32)f2bf(a0) | ((u32)f2bf(a1)<<16);
  p.y = (u32)f2bf(a2) | ((u32)f2bf(a3)<<16);
  *(uint2*)(bvb + o) = p;
}

// graph head: g_max + gather head/tail rows -> g_G [64][768] f32 (position space)
__global__ void gmax_k(const float* __restrict__ bv, const int* __restrict__ heads,
                       const int* __restrict__ tails, float* __restrict__ gG){
  int g = blockIdx.x, col = threadIdx.x;
  float mx = -1e30f;
  const float* p = bv + (size_t)g*256*HD + col;
  for (int i=0; i<256; ++i) mx = fmaxf(mx, p[(size_t)i*HD]);
  gG[g*768 + col]       = mx;
  gG[g*768 + 256 + col] = bv[(size_t)heads[g]*HD + col];
  gG[g*768 + 512 + col] = bv[(size_t)tails[g]*HD + col];
}

// 1024 threads: k-loop split 4 ways (kc = tid>>8), LDS combine before relu.
__global__ __launch_bounds__(1024)
void glog_k(const float* __restrict__ gG, const float* __restrict__ w1,
            const float* __restrict__ b1, const float* __restrict__ w2,
            const float* __restrict__ b2, float* __restrict__ logits){
  __shared__ float part[4][256];
  __shared__ float red[16];
  int g = blockIdx.x;
  int n  = threadIdx.x & 255;
  int kc = threadIdx.x >> 8;
  const float* gg = gG + g*768;
  float a = 0.f;
  for (int k=kc*192; k<kc*192+192; ++k){
    int b = k >> 8, p = k & 255;
    int f = (p>>6)*64 + (p&3)*16 + ((p>>2)&15);   // inv(p)
    a += gg[k] * w1[(size_t)(b*256 + f)*HD + n];
  }
  part[kc][n] = a;
  __syncthreads();
  float v = 0.f;
  if (threadIdx.x < 256){
    v = b1[n] + part[0][n] + part[1][n] + part[2][n] + part[3][n];
    v = fmaxf(v, 0.f) * w2[n];
  }
#pragma unroll
  for (int d=1; d<64; d<<=1) v += __shfl_xor(v, d, 64);
  if ((threadIdx.x & 63) == 0) red[threadIdx.x >> 6] = v;
  __syncthreads();
  if (threadIdx.x == 0){
    float t = 0.f;
#pragma unroll
    for (int i=0; i<16; ++i) t += red[i];
    logits[g] = t + b2[0];
  }
}

__global__ void gfin_k(const float* __restrict__ gG, const float* __restrict__ logits,
                       float* __restrict__ out){
  int tid = threadIdx.x;
  float m = -1e30f;
  for (int g=0; g<NG; ++g) m = fmaxf(m, logits[g]);
  float s = 0.f;
  for (int g=0; g<NG; ++g) s += __expf(logits[g] - m);
  float inv = 1.f/s;
  for (int j=tid; j<768; j+=256){
    int b = j >> 8, f = j & 255;
    int p = (f>>6)*64 + (f&15)*4 + ((f>>4)&3);    // pi(f): un-permute for output
    float o = 0.f;
    for (int g=0; g<NG; ++g) o += __expf(logits[g]-m)*inv * gG[g*768 + b*256 + p];
    out[j] = o;
  }
}

extern "C" void kernel_launch(void* const* d_in, const int* in_sizes, int n_in,
                              void* d_out, int out_size, void* d_ws, size_t ws_size,
                              hipStream_t stream)
{
  const float* ef    = (const float*)d_in[0];
  const float* gall  = (const float*)d_in[1];
  const float* ea_w1 = (const float*)d_in[2];
  const float* ea_b1 = (const float*)d_in[3];
  const float* ea_w2 = (const float*)d_in[4];
  const float* ea_b2 = (const float*)d_in[5];
  const float* eu_w1 = (const float*)d_in[6];
  const float* eu_b1 = (const float*)d_in[7];
  const float* eu_w2 = (const float*)d_in[8];
  const float* eu_b2 = (const float*)d_in[9];
  const float* gw_w1 = (const float*)d_in[10];
  const float* gw_b1 = (const float*)d_in[11];
  const float* gw_w2 = (const float*)d_in[12];
  const float* gw_b2 = (const float*)d_in[13];
  const float* ew_w  = (const float*)d_in[14];
  const float* ew_b  = (const float*)d_in[15];
  const int* eidx    = (const int*)d_in[16];
  const int* srcI    = eidx;
  const int* recvI   = eidx + NE;
  const int* ndeg    = (const int*)d_in[17];
  const int* batch   = (const int*)d_in[18];
  const int* heads   = (const int*)d_in[19];
  const int* tails   = (const int*)d_in[20];
  float* out = (float*)d_out;

  char* wsb = (char*)d_ws;
  size_t off = 0;
  auto alloc = [&](size_t sz)->char*{
    char* p = wsb + off; off = (off + sz + 255) & ~(size_t)255; return p;
  };
  u16*   BE    = (u16*)  alloc((size_t)NE*HD*2);
  float* score = (float*)alloc((size_t)NE*4);
  u16*   P     = (u16*)  alloc((size_t)NN*HD*2);
  u16*   Q     = (u16*)  alloc((size_t)NN*HD*2);
  float* bv    = (float*)alloc((size_t)NN*HD*4);
  u16*   bvb   = (u16*)  alloc((size_t)NN*HD*2);
  int*   offs  = (int*)  alloc((size_t)(NN+1)*4);
  int*   cur   = (int*)  alloc((size_t)NN*4);
  int*   eids  = (int*)  alloc((size_t)NE*4);
  float* flags = (float*)alloc((size_t)NN*8);
  u16*   eaw1f = (u16*)  alloc((size_t)65536*2);
  u16*   w1af  = (u16*)  alloc((size_t)65536*2);
  u16*   w1bf  = (u16*)  alloc((size_t)65536*2);
  u16*   w1cf  = (u16*)  alloc((size_t)65536*2);
  u16*   euw2f = (u16*)  alloc((size_t)65536*2);
  float* gG    = (float*)alloc((size_t)NG*768*4);
  float* logits= (float*)alloc((size_t)NG*4);

  // one-time per launch: weight repacks + b_e init + flags + CSR
  repack_k<<<32,256,0,stream>>>(ea_w1, eaw1f);
  repack_k<<<32,256,0,stream>>>(eu_w1, w1af);              // rows 0..255   (src b_v part)
  repack_k<<<32,256,0,stream>>>(eu_w1 + 258*HD, w1bf);     // rows 258..513 (recv b_v part)
  repack_k<<<32,256,0,stream>>>(eu_w1 + 516*HD, w1cf);     // rows 516..771 (b_e part)
  repack_k<<<32,256,0,stream>>>(eu_w2, euw2f);
  initbe_k<<<NE*64/256,256,0,stream>>>(ef, gall, BE);
  flags_k<<<NN/256,256,0,stream>>>(batch, heads, tails, flags);
  scan_k<<<1,256,0,stream>>>(ndeg, offs, cur);
  fill_k<<<NE/256,256,0,stream>>>(recvI, cur, eids);

  // score for iter0 (reads the freshly-built BE)
  gemm_k<MODE_SCORE><<<NE/64,256,0,stream>>>(BE, eaw1f, nullptr, score,
      nullptr, nullptr, ea_b1, ea_w2, ea_b2, nullptr, nullptr, nullptr);

  for (int it=0; it<3; ++it){
    // scatter-softmax + degree-normalized aggregation -> b_v (f32 + bf16)
    agg_k<<<NN/4,256,0,stream>>>(score, BE, offs, eids, bv, bvb);
    // P = r_v@W1a + b1 ; Q = r_v@W1b (one dispatch, grid.y selects half)
    gemm_k<MODE_PQ><<<dim3(NN/64,2),256,0,stream>>>(bvb, w1af, w1bf, nullptr,
        P, Q, eu_b1, nullptr, nullptr, flags, eu_w1 + 256*HD, eu_w1 + 514*HD);
    // fused edge update (+ next score, or final w_e)
    if (it < 2){
      mega_k<false><<<NE/64,256,0,stream>>>(BE, w1cf, euw2f, eaw1f,
          score, nullptr, P, Q, srcI, recvI, eu_b2,
          ea_b1, ea_w2, ea_b2, nullptr, nullptr);
    } else {
      mega_k<true><<<NE/64,256,0,stream>>>(BE, w1cf, euw2f, eaw1f,
          nullptr, out, P, Q, srcI, recvI, eu_b2,
          nullptr, nullptr, nullptr, ew_w, ew_b);
    }
  }

  // graph head (f32 exact, tiny; un-permutes positions)
  gmax_k<<<NG,256,0,stream>>>(bv, heads, tails, gG);
  glog_k<<<NG,1024,0,stream>>>(gG, gw_w1, gw_b1, gw_w2, gw_b2, logits);
  gfin_k<<<1,256,0,stream>>>(gG, logits, out + NE);
}

// Round 9
// 883.967 us; speedup vs baseline: 1.1762x; 1.1213x over previous
//
#include <hip/hip_runtime.h>
#include <stdint.h>

typedef unsigned short u16;
typedef unsigned int   u32;

#define NN 16384   // nodes
#define NE 262144  // edges
#define NG 64      // graphs
#define HD 256     // hidden
#define SHS 264    // row-major LDS tile stride in u16 (+8 pad -> 2-way-free banks)

typedef __attribute__((ext_vector_type(8))) short bfrag;  // 8 bf16 (4 VGPR)
typedef __attribute__((ext_vector_type(4))) float ffrag;  // 4 f32 acc

__device__ __forceinline__ float bf2f(u16 h){
  union { u32 u; float f; } v; v.u = ((u32)h) << 16; return v.f;
}
__device__ __forceinline__ u16 f2bf(float x){
  union { float f; u32 u; } v; v.f = x;
  u32 r = v.u + 0x7fffu + ((v.u >> 16) & 1u);
  return (u16)(r >> 16);
}
__device__ __forceinline__ float sigmoidf(float x){ return 1.f/(1.f+__expf(-x)); }

// async global->LDS DMA, 16B/lane: lane i lands at (wave-uniform base) + i*16
__device__ __forceinline__ void dma16(const void* g, void* l){
  __builtin_amdgcn_global_load_lds(
      (const __attribute__((address_space(1))) u32*)g,
      (__attribute__((address_space(3))) u32*)l, 16, 0, 0);
}

// Feature permutation pi: feature f lives at position p(f)=(f>>6)*64+(f&15)*4
// +((f>>4)&3); inv(p)=(p>>6)*64+(p&3)*16+((p>>2)&15). Weights repacked with
// K-rows permuted by inv(). Epilogues write packed uint2; P/Q gathers are one
// uint2 per row.
//
// R15 = R14 (991us best) + dispatch/de-chain trims outside mega:
//  * score buffer now holds exp(sigmoid(v)) (producers: SCORE epilogue,
//    mega GEMM3 epilogue). score is workspace-internal, only agg consumes
//    it as expf(score) -- identical f32 math, moved out of agg's per-edge
//    dependent chain. agg loop unroll 4 to overlap gather chains.
//  * prep_k merges 5x repack + flags_k into one 224-block dispatch.
//  * gmaxlog_k merges gmax+glog (64 x 1024): per-graph gG row staged in
//    LDS, glog k-loop reads LDS. Dispatches 22 -> 16.

enum { MODE_SCORE=0, MODE_PQ=4 };

// SCORE: outF = exp(sigmoid(relu(A@Bf0+bias)@vec + scal))  (per-row scalar)
// PQ (grid.y=0/1): out{0,1} = A@Bf{0,1} [+bias] + flag-rank1(ht{0,1})
template<int MODE>
__global__ __launch_bounds__(256, 4)
void gemm_k(const u16* __restrict__ A, const u16* __restrict__ Bf0,
            const u16* __restrict__ Bf1,
            float* __restrict__ outF, u16* __restrict__ out0, u16* __restrict__ out1,
            const float* __restrict__ bias, const float* __restrict__ vec,
            const float* __restrict__ scal, const float* __restrict__ flags,
            const float* __restrict__ ht0, const float* __restrict__ ht1)
{
  __shared__ __align__(16) u16 sA[16384];   // 32KB, frag layout [(c*4+mt)*512 + l*8]
  __shared__ float sred[4][64];

  const int l  = threadIdx.x & 63;
  const int w  = threadIdx.x >> 6;
  const int q  = l >> 4;
  const int ml = l & 15;
  const long rowBase = (long)blockIdx.x * 64;

  const u16* Bf   = Bf0;
  u16*       outB = out0;
  const float* htp = ht0;
  const float* bp  = bias;
  if (MODE==MODE_PQ && blockIdx.y){ Bf = Bf1; outB = out1; htp = ht1; bp = nullptr; }

  // stage A tile once (frag layout); init-acc loads fly under the staging drain
  const u16* gA = A + (size_t)(rowBase + w*16 + ml)*HD + q*8;
#pragma unroll
  for (int c=0; c<8; ++c) dma16(gA + c*32, sA + (c*4+w)*512);

  ffrag acc[4][4];
  if constexpr (MODE==MODE_SCORE){
#pragma unroll
    for (int n=0; n<4; ++n){
      const float bb = bias[(w*4+n)*16+ml];
#pragma unroll
      for (int mt=0; mt<4; ++mt) acc[mt][n] = (ffrag){bb,bb,bb,bb};
    }
  } else {
    float h0[4], h1[4], bb[4];
#pragma unroll
    for (int n=0; n<4; ++n){
      const int col = (w*4+n)*16+ml;
      h0[n] = htp[col]; h1[n] = htp[HD+col]; bb[n] = bp ? bp[col] : 0.f;
    }
    float2 fl[16];
#pragma unroll
    for (int i=0; i<16; ++i){
      long row = rowBase + (i>>2)*16 + q*4 + (i&3);
      fl[i] = *(const float2*)(flags + 2*row);
    }
#pragma unroll
    for (int i=0; i<16; ++i){
      const int mt = i>>2, r = i&3;
      const float fh = fl[i].x, ft = fl[i].y;
#pragma unroll
      for (int n=0; n<4; ++n)
        acc[mt][n][r] = bb[n] + fh*h0[n] + ft*h1[n];
    }
  }
  __syncthreads();

  __builtin_amdgcn_s_setprio(1);
#pragma unroll 1
  for (int c=0; c<8; ++c){
    bfrag a[4], b[4];
#pragma unroll
    for (int n=0; n<4; ++n)
      b[n] = *(const bfrag*)(Bf + (((size_t)c*16 + w*4 + n)*64 + l)*8);
#pragma unroll
    for (int mt=0; mt<4; ++mt) a[mt] = *(const bfrag*)(sA + (c*4+mt)*512 + l*8);
#pragma unroll
    for (int mt=0; mt<4; ++mt)
#pragma unroll
      for (int n=0; n<4; ++n)
        acc[mt][n] = __builtin_amdgcn_mfma_f32_16x16x32_bf16(a[mt], b[n], acc[mt][n], 0, 0, 0);
  }
  __builtin_amdgcn_s_setprio(0);

  if constexpr (MODE==MODE_SCORE){
    float part[4][4];
#pragma unroll
    for (int mt=0; mt<4; ++mt)
#pragma unroll
      for (int r=0; r<4; ++r) part[mt][r] = 0.f;
#pragma unroll
    for (int n=0; n<4; ++n){
      const float vvn = vec[(w*4+n)*16+ml];
#pragma unroll
      for (int mt=0; mt<4; ++mt)
#pragma unroll
        for (int r=0; r<4; ++r)
          part[mt][r] += fmaxf(acc[mt][n][r], 0.f) * vvn;   // bias in acc-init
    }
#pragma unroll
    for (int mt=0; mt<4; ++mt)
#pragma unroll
      for (int r=0; r<4; ++r){
        float p = part[mt][r];
        p += __shfl_xor(p, 1, 64); p += __shfl_xor(p, 2, 64);
        p += __shfl_xor(p, 4, 64); p += __shfl_xor(p, 8, 64);
        part[mt][r] = p;
      }
    if (ml == 0)
#pragma unroll
      for (int mt=0; mt<4; ++mt)
#pragma unroll
        for (int r=0; r<4; ++r)
          sred[w][mt*16 + q*4 + r] = part[mt][r];
    __syncthreads();
    if (threadIdx.x < 64){
      const int t = threadIdx.x;
      float v = sred[0][t] + sred[1][t] + sred[2][t] + sred[3][t];
      outF[rowBase + t] = __expf(sigmoidf(v + scal[0]));   // pre-exp'd for agg
    }
  } else { // MODE_PQ: all additive terms already in acc-init
#pragma unroll
    for (int mt=0; mt<4; ++mt)
#pragma unroll
      for (int r=0; r<4; ++r){
        long row = rowBase + mt*16 + q*4 + r;
        u16 o[4];
#pragma unroll
        for (int n=0; n<4; ++n) o[n] = f2bf(acc[mt][n][r]);
        uint2 pk; pk.x = (u32)o[0] | ((u32)o[1]<<16); pk.y = (u32)o[2] | ((u32)o[3]<<16);
        *(uint2*)(outB + (size_t)row*HD + w*64 + ml*4) = pk;
      }
  }
}

// ---- MEGA: per-iteration fused edge pipeline (3 chained GEMMs, one LDS tile) ----
// GEMM1: h = relu(BE@W1c + P[src]+Q[recv]); GEMM2: b_e' = h@W2 + b2;
// !LAST: BE'=b_e' to HBM, GEMM3: score' = exp(sigmoid(relu(b_e'@ea_w1+b1)@ea_w2+b2))
// LAST:  w_e = sigmoid(b_e'@ew_w+ew_b) directly (b_e' never stored).
template<bool LAST>
__global__ __launch_bounds__(256, 4)
void mega_k(u16* __restrict__ BE, const u16* __restrict__ w1cf,
            const u16* __restrict__ w2f, const u16* __restrict__ eaw1f,
            float* __restrict__ scoreOut, float* __restrict__ weOut,
            const u16* __restrict__ Pg, const u16* __restrict__ Qg,
            const int* __restrict__ srcI, const int* __restrict__ recvI,
            const float* __restrict__ b2,
            const float* __restrict__ sb1, const float* __restrict__ sv,
            const float* __restrict__ ssc,
            const float* __restrict__ wv, const float* __restrict__ wb)
{
  // one buffer, two lifetimes: frag-layout staged BE (32KB), then row-major-264
  // h / b_e' (33792B). Transitions guarded by barriers.
  __shared__ __align__(16) u16 sU[64*SHS];   // 33792B
  __shared__ float sred[4][64];
  __shared__ int sIdx[128];                  // src[0:64], recv[64:128]

  const int l  = threadIdx.x & 63;
  const int w  = threadIdx.x >> 6;
  const int q  = l >> 4;
  const int ml = l & 15;
  const long rowBase = (long)blockIdx.x * 64;

  // ---- stage BE tile once (frag layout) ----
  const u16* gA = BE + (size_t)(rowBase + w*16 + ml)*HD + q*8;
#pragma unroll
  for (int c=0; c<8; ++c) dma16(gA + c*32, sU + (c*4+w)*512);
  __syncthreads();

  // idx pre-stage: issued here, hidden under GEMM1; ordered by GEMM1-end barrier
  if (threadIdx.x < 128){
    const int t = threadIdx.x;
    sIdx[t] = (t < 64) ? srcI[rowBase + t] : recvI[rowBase + (t - 64)];
  }

  ffrag acc[4][4];
#pragma unroll
  for (int mt=0; mt<4; ++mt)
#pragma unroll
    for (int n=0; n<4; ++n) acc[mt][n] = (ffrag){0.f,0.f,0.f,0.f};

  // ---- GEMM1 (barrier-free): A = sU frag, B = w1cf global ----
  __builtin_amdgcn_s_setprio(1);
#pragma unroll 1
  for (int c=0; c<8; ++c){
    bfrag a[4], b[4];
#pragma unroll
    for (int n=0; n<4; ++n)
      b[n] = *(const bfrag*)(w1cf + (((size_t)c*16 + w*4 + n)*64 + l)*8);
#pragma unroll
    for (int mt=0; mt<4; ++mt) a[mt] = *(const bfrag*)(sU + (c*4+mt)*512 + l*8);
#pragma unroll
    for (int mt=0; mt<4; ++mt)
#pragma unroll
      for (int n=0; n<4; ++n)
        acc[mt][n] = __builtin_amdgcn_mfma_f32_16x16x32_bf16(a[mt], b[n], acc[mt][n], 0, 0, 0);
  }
  __builtin_amdgcn_s_setprio(0);
  __syncthreads();   // all sU(frag) reads done before overwrite

  // ---- epilogue1: h = relu(acc + P[src] + Q[recv]) -> sU row-major-264 ----
#pragma unroll
  for (int mt=0; mt<4; ++mt)
#pragma unroll
    for (int r=0; r<4; ++r){
      const int rl = mt*16 + q*4 + r;
      const int si = sIdx[rl];
      const int ri = sIdx[64 + rl];
      uint2 pu = *(const uint2*)(Pg + (size_t)si*HD + w*64 + ml*4);
      uint2 qu = *(const uint2*)(Qg + (size_t)ri*HD + w*64 + ml*4);
      u16 o[4];
      float pv[4] = { bf2f((u16)(pu.x & 0xffff)), bf2f((u16)(pu.x >> 16)),
                      bf2f((u16)(pu.y & 0xffff)), bf2f((u16)(pu.y >> 16)) };
      float qv[4] = { bf2f((u16)(qu.x & 0xffff)), bf2f((u16)(qu.x >> 16)),
                      bf2f((u16)(qu.y & 0xffff)), bf2f((u16)(qu.y >> 16)) };
#pragma unroll
      for (int n=0; n<4; ++n)
        o[n] = f2bf(fmaxf(acc[mt][n][r] + pv[n] + qv[n], 0.f));
      uint2 pk; pk.x = (u32)o[0] | ((u32)o[1]<<16); pk.y = (u32)o[2] | ((u32)o[3]<<16);
      *(uint2*)(sU + (size_t)rl*SHS + w*64 + ml*4) = pk;
    }
  __syncthreads();

  // ---- GEMM2 (barrier-free): A = sU row-major, B = w2f global ----
#pragma unroll
  for (int mt=0; mt<4; ++mt)
#pragma unroll
    for (int n=0; n<4; ++n) acc[mt][n] = (ffrag){0.f,0.f,0.f,0.f};
  __builtin_amdgcn_s_setprio(1);
#pragma unroll 1
  for (int c=0; c<8; ++c){
    bfrag a[4], b[4];
#pragma unroll
    for (int n=0; n<4; ++n)
      b[n] = *(const bfrag*)(w2f + (((size_t)c*16 + w*4 + n)*64 + l)*8);
#pragma unroll
    for (int mt=0; mt<4; ++mt)
      a[mt] = *(const bfrag*)(sU + (size_t)(mt*16+ml)*SHS + c*32 + q*8);
#pragma unroll
    for (int mt=0; mt<4; ++mt)
#pragma unroll
      for (int n=0; n<4; ++n)
        acc[mt][n] = __builtin_amdgcn_mfma_f32_16x16x32_bf16(a[mt], b[n], acc[mt][n], 0, 0, 0);
  }
  __builtin_amdgcn_s_setprio(0);

  float bia2[4];
#pragma unroll
  for (int n=0; n<4; ++n) bia2[n] = b2[(w*4+n)*16+ml];

  if constexpr (!LAST){
    __syncthreads();   // all sU reads of GEMM2 done before overwrite
    // epilogue2: b_e' -> global BE (in-place) + sU row-major for GEMM3
#pragma unroll
    for (int mt=0; mt<4; ++mt)
#pragma unroll
      for (int r=0; r<4; ++r){
        long row = rowBase + mt*16 + q*4 + r;
        u16 o[4];
#pragma unroll
        for (int n=0; n<4; ++n) o[n] = f2bf(acc[mt][n][r] + bia2[n]);
        uint2 pk; pk.x = (u32)o[0] | ((u32)o[1]<<16); pk.y = (u32)o[2] | ((u32)o[3]<<16);
        *(uint2*)(BE + (size_t)row*HD + w*64 + ml*4) = pk;
        *(uint2*)(sU + (size_t)(mt*16 + q*4 + r)*SHS + w*64 + ml*4) = pk;
      }
    __syncthreads();

    // ---- GEMM3 (barrier-free): A = sU row-major, B = eaw1f global ----
#pragma unroll
    for (int mt=0; mt<4; ++mt)
#pragma unroll
      for (int n=0; n<4; ++n) acc[mt][n] = (ffrag){0.f,0.f,0.f,0.f};
    __builtin_amdgcn_s_setprio(1);
#pragma unroll 1
    for (int c=0; c<8; ++c){
      bfrag a[4], b[4];
#pragma unroll
      for (int n=0; n<4; ++n)
        b[n] = *(const bfrag*)(eaw1f + (((size_t)c*16 + w*4 + n)*64 + l)*8);
#pragma unroll
      for (int mt=0; mt<4; ++mt)
        a[mt] = *(const bfrag*)(sU + (size_t)(mt*16+ml)*SHS + c*32 + q*8);
#pragma unroll
      for (int mt=0; mt<4; ++mt)
#pragma unroll
        for (int n=0; n<4; ++n)
          acc[mt][n] = __builtin_amdgcn_mfma_f32_16x16x32_bf16(a[mt], b[n], acc[mt][n], 0, 0, 0);
    }
    __builtin_amdgcn_s_setprio(0);
    float part[4][4];
#pragma unroll
    for (int mt=0; mt<4; ++mt)
#pragma unroll
      for (int r=0; r<4; ++r) part[mt][r] = 0.f;
#pragma unroll
    for (int n=0; n<4; ++n){
      const int col = (w*4+n)*16+ml;
      const float bb = sb1[col], vvn = sv[col];
#pragma unroll
      for (int mt=0; mt<4; ++mt)
#pragma unroll
        for (int r=0; r<4; ++r)
          part[mt][r] += fmaxf(acc[mt][n][r] + bb, 0.f) * vvn;
    }
#pragma unroll
    for (int mt=0; mt<4; ++mt)
#pragma unroll
      for (int r=0; r<4; ++r){
        float p = part[mt][r];
        p += __shfl_xor(p, 1, 64); p += __shfl_xor(p, 2, 64);
        p += __shfl_xor(p, 4, 64); p += __shfl_xor(p, 8, 64);
        part[mt][r] = p;
      }
    if (ml == 0)
#pragma unroll
      for (int mt=0; mt<4; ++mt)
#pragma unroll
        for (int r=0; r<4; ++r)
          sred[w][mt*16 + q*4 + r] = part[mt][r];
    __syncthreads();
    if (threadIdx.x < 64){
      const int t = threadIdx.x;
      float v = sred[0][t] + sred[1][t] + sred[2][t] + sred[3][t];
      scoreOut[rowBase + t] = __expf(sigmoidf(v + ssc[0]));   // pre-exp'd for agg
    }
  } else {
    // last iter: w_e = sigmoid(b_e' . ew_w + ew_b)
    float part[4][4];
#pragma unroll
    for (int mt=0; mt<4; ++mt)
#pragma unroll
      for (int r=0; r<4; ++r) part[mt][r] = 0.f;
#pragma unroll
    for (int n=0; n<4; ++n){
      const float vvn = wv[(w*4+n)*16+ml];
#pragma unroll
      for (int mt=0; mt<4; ++mt)
#pragma unroll
        for (int r=0; r<4; ++r)
          part[mt][r] += (acc[mt][n][r] + bia2[n]) * vvn;
    }
#pragma unroll
    for (int mt=0; mt<4; ++mt)
#pragma unroll
      for (int r=0; r<4; ++r){
        float p = part[mt][r];
        p += __shfl_xor(p, 1, 64); p += __shfl_xor(p, 2, 64);
        p += __shfl_xor(p, 4, 64); p += __shfl_xor(p, 8, 64);
        part[mt][r] = p;
      }
    if (ml == 0)
#pragma unroll
      for (int mt=0; mt<4; ++mt)
#pragma unroll
        for (int r=0; r<4; ++r)
          sred[w][mt*16 + q*4 + r] = part[mt][r];
    __syncthreads();
    if (threadIdx.x < 64){
      const int t = threadIdx.x;
      float v = sred[0][t] + sred[1][t] + sred[2][t] + sred[3][t];
      weOut[rowBase + t] = sigmoidf(v + wb[0]);
    }
  }
}

// ---- PREP: 5x weight repack (blocks 0..159) + flags (blocks 160..223) ----
// repack B[256 x 256] f32 row-major -> bf16 frag layout [c][n][lane][8],
// K-rows permuted: packed row kp takes source feature inv(kp).
__global__ void prep_k(const float* __restrict__ ea_w1, u16* __restrict__ eaw1f,
                       const float* __restrict__ eu_w1, u16* __restrict__ w1af,
                       u16* __restrict__ w1bf, u16* __restrict__ w1cf,
                       const float* __restrict__ eu_w2, u16* __restrict__ euw2f,
                       const int* __restrict__ batch, const int* __restrict__ heads,
                       const int* __restrict__ tails, float* __restrict__ flags){
  const int bb = blockIdx.x;
  if (bb < 160){
    const float* B; u16* out;
    switch (bb >> 5){
      case 0:  B = ea_w1;            out = eaw1f; break;
      case 1:  B = eu_w1;            out = w1af;  break;
      case 2:  B = eu_w1 + 258*HD;   out = w1bf;  break;
      case 3:  B = eu_w1 + 516*HD;   out = w1cf;  break;
      default: B = eu_w2;            out = euw2f; break;
    }
    int t = (bb & 31)*256 + threadIdx.x;         // 8192 per matrix
    int l = t & 63, n = (t>>6)&15, c = t>>10;
    int col = n*16 + (l&15);
    int kbase = c*32 + ((l>>4)<<3);
#pragma unroll
    for (int j=0; j<8; ++j){
      int kp = kbase + j;
      int f = (kp>>6)*64 + (kp&3)*16 + ((kp>>2)&15);   // inv(kp)
      out[(size_t)t*8 + j] = f2bf(B[(size_t)f*HD + col]);
    }
  } else {
    int n = (bb - 160)*256 + threadIdx.x;
    int g = batch[n];
    flags[2*n]   = (n == heads[g]) ? 1.f : 0.f;
    flags[2*n+1] = (n == tails[g]) ? 1.f : 0.f;
  }
}

// b_e(iter0) = [edge_features | g_all] -> bf16, position-permuted layout
__global__ void initbe_k(const float* __restrict__ ef, const float* __restrict__ gall,
                         u16* __restrict__ BE){
  int t = blockIdx.x*256 + threadIdx.x;        // NE*64
  int e = t >> 6; int p4 = (t & 63) * 4;
  int w64 = p4 >> 6, mlr = (p4 >> 2) & 15;
  u16 o[4];
#pragma unroll
  for (int i=0; i<4; ++i){
    int f = w64*64 + i*16 + mlr;                 // inv(p4+i)
    float v = (f < 192) ? ef[(size_t)e*192 + f] : gall[f - 192];
    o[i] = f2bf(v);
  }
  uint2 pk; pk.x = (u32)o[0] | ((u32)o[1]<<16); pk.y = (u32)o[2] | ((u32)o[3]<<16);
  *(uint2*)(BE + (size_t)e*HD + p4) = pk;
}

// exclusive prefix sum of degrees -> CSR offsets (+ cursor copy), single block
__global__ void scan_k(const int* __restrict__ deg, int* __restrict__ offs,
                       int* __restrict__ cur){
  __shared__ int part[256];
  int tid = threadIdx.x;
  int base = tid * 64;
  int s = 0;
  for (int j=0; j<64; ++j) s += deg[base+j];
  part[tid] = s;
  __syncthreads();
  if (tid == 0){
    int run = 0;
    for (int i=0; i<256; ++i){ int t = part[i]; part[i] = run; run += t; }
  }
  __syncthreads();
  int run = part[tid];
  for (int j=0; j<64; ++j){
    offs[base+j] = run; cur[base+j] = run; run += deg[base+j];
  }
  if (tid == 255) offs[NN] = run;
}

__global__ void fill_k(const int* __restrict__ recv, int* __restrict__ cur,
                       int* __restrict__ eids){
  int e = blockIdx.x*256 + threadIdx.x;
  int r = recv[e];
  int p = atomicAdd(&cur[r], 1);
  eids[p] = e;
}

// per-node softmax over incoming edges + weighted aggregation, one wave per node.
// score[] already holds exp(sigmoid(.)) from the producers; max-shift is an
// exact no-op since the pre-exp values lie in (0,1). Single fused pass.
__global__ __launch_bounds__(256)
void agg_k(const float* __restrict__ score, const u16* __restrict__ BE,
           const int* __restrict__ offs, const int* __restrict__ eids,
           float* __restrict__ bv, u16* __restrict__ bvb){
  int node = blockIdx.x*4 + (threadIdx.x >> 6);
  int l = threadIdx.x & 63;
  int beg = offs[node], end = offs[node+1];

  float s = 0.f;
  float a0=0.f, a1=0.f, a2=0.f, a3=0.f;
#pragma unroll 4
  for (int i=beg; i<end; ++i){
    int e = eids[i];
    float al = score[e];                        // pre-exp'd
    uint2 uv = *(const uint2*)(BE + (size_t)e*HD + l*4);
    s  += al;
    a0 += al * bf2f((u16)(uv.x & 0xffff));
    a1 += al * bf2f((u16)(uv.x >> 16));
    a2 += al * bf2f((u16)(uv.y & 0xffff));
    a3 += al * bf2f((u16)(uv.y >> 16));
  }
  float deg = (float)(end - beg);
  float scale = (end > beg) ? (1.f/s) * (1.f/(1.f+deg)) : 0.f;

  size_t o = (size_t)node*HD + l*4;
  a0 *= scale; a1 *= scale; a2 *= scale; a3 *= scale;
  bv[o+0]=a0; bv[o+1]=a1; bv[o+2]=a2; bv[o+3]=a3;
  uint2 p; p.x = (u32)f2bf(a0) | ((u32)f2bf(a1)<<16);
  p.y = (u32)f2bf(a2) | ((u32)f2bf(a3)<<16);
  *(uint2*)(bvb + o) = p;
}

// ---- merged graph head: g_max + head/tail gather + logits, one block/graph ----
// phase1: 4-way row-split max -> gG global + sG LDS; phase2: glog k-loop from LDS.
__global__ __launch_bounds__(1024)
void gmaxlog_k(const float* __restrict__ bv, const int* __restrict__ heads,
               const int* __restrict__ tails, float* __restrict__ gG,
               const float* __restrict__ w1, const float* __restrict__ b1,
               const float* __restrict__ w2, const float* __restrict__ b2,
               float* __restrict__ logits){
  __shared__ float sG[768];
  __shared__ float pbuf[4][256];
  __shared__ float red[16];
  const int g  = blockIdx.x;
  const int n  = threadIdx.x & 255;
  const int kc = threadIdx.x >> 8;

  // phase 1: partial max over 64 rows each
  const float* p = bv + (size_t)g*256*HD + n;
  float mx = -1e30f;
  for (int i=kc*64; i<kc*64+64; ++i) mx = fmaxf(mx, p[(size_t)i*HD]);
  pbuf[kc][n] = mx;
  __syncthreads();
  if (threadIdx.x < 256){
    float m2 = fmaxf(fmaxf(pbuf[0][n], pbuf[1][n]), fmaxf(pbuf[2][n], pbuf[3][n]));
    float hv = bv[(size_t)heads[g]*HD + n];
    float tv = bv[(size_t)tails[g]*HD + n];
    gG[g*768 + n]       = m2;
    gG[g*768 + 256 + n] = hv;
    gG[g*768 + 512 + n] = tv;
    sG[n] = m2; sG[256+n] = hv; sG[512+n] = tv;
  }
  __syncthreads();

  // phase 2: logits (k-loop 4-way split, gG row from LDS)
  float a = 0.f;
  for (int k=kc*192; k<kc*192+192; ++k){
    int b = k >> 8, pp = k & 255;
    int f = (pp>>6)*64 + (pp&3)*16 + ((pp>>2)&15);   // inv(pp)
    a += sG[k] * w1[(size_t)(b*256 + f)*HD + n];
  }
  pbuf[kc][n] = a;
  __syncthreads();
  float v = 0.f;
  if (threadIdx.x < 256){
    v = b1[n] + pbuf[0][n] + pbuf[1][n] + pbuf[2][n] + pbuf[3][n];
    v = fmaxf(v, 0.f) * w2[n];
  }
#pragma unroll
  for (int d=1; d<64; d<<=1) v += __shfl_xor(v, d, 64);
  if ((threadIdx.x & 63) == 0) red[threadIdx.x >> 6] = v;
  __syncthreads();
  if (threadIdx.x == 0){
    float t = 0.f;
#pragma unroll
    for (int i=0; i<16; ++i) t += red[i];
    logits[g] = t + b2[0];
  }
}

__global__ void gfin_k(const float* __restrict__ gG, const float* __restrict__ logits,
                       float* __restrict__ out){
  int tid = threadIdx.x;
  float m = -1e30f;
  for (int g=0; g<NG; ++g) m = fmaxf(m, logits[g]);
  float s = 0.f;
  for (int g=0; g<NG; ++g) s += __expf(logits[g] - m);
  float inv = 1.f/s;
  for (int j=tid; j<768; j+=256){
    int b = j >> 8, f = j & 255;
    int p = (f>>6)*64 + (f&15)*4 + ((f>>4)&3);    // pi(f): un-permute for output
    float o = 0.f;
    for (int g=0; g<NG; ++g) o += __expf(logits[g]-m)*inv * gG[g*768 + b*256 + p];
    out[j] = o;
  }
}

extern "C" void kernel_launch(void* const* d_in, const int* in_sizes, int n_in,
                              void* d_out, int out_size, void* d_ws, size_t ws_size,
                              hipStream_t stream)
{
  const float* ef    = (const float*)d_in[0];
  const float* gall  = (const float*)d_in[1];
  const float* ea_w1 = (const float*)d_in[2];
  const float* ea_b1 = (const float*)d_in[3];
  const float* ea_w2 = (const float*)d_in[4];
  const float* ea_b2 = (const float*)d_in[5];
  const float* eu_w1 = (const float*)d_in[6];
  const float* eu_b1 = (const float*)d_in[7];
  const float* eu_w2 = (const float*)d_in[8];
  const float* eu_b2 = (const float*)d_in[9];
  const float* gw_w1 = (const float*)d_in[10];
  const float* gw_b1 = (const float*)d_in[11];
  const float* gw_w2 = (const float*)d_in[12];
  const float* gw_b2 = (const float*)d_in[13];
  const float* ew_w  = (const float*)d_in[14];
  const float* ew_b  = (const float*)d_in[15];
  const int* eidx    = (const int*)d_in[16];
  const int* srcI    = eidx;
  const int* recvI   = eidx + NE;
  const int* ndeg    = (const int*)d_in[17];
  const int* batch   = (const int*)d_in[18];
  const int* heads   = (const int*)d_in[19];
  const int* tails   = (const int*)d_in[20];
  float* out = (float*)d_out;

  char* wsb = (char*)d_ws;
  size_t off = 0;
  auto alloc = [&](size_t sz)->char*{
    char* p = wsb + off; off = (off + sz + 255) & ~(size_t)255; return p;
  };
  u16*   BE    = (u16*)  alloc((size_t)NE*HD*2);
  float* score = (float*)alloc((size_t)NE*4);
  u16*   P     = (u16*)  alloc((size_t)NN*HD*2);
  u16*   Q     = (u16*)  alloc((size_t)NN*HD*2);
  float* bv    = (float*)alloc((size_t)NN*HD*4);
  u16*   bvb   = (u16*)  alloc((size_t)NN*HD*2);
  int*   offs  = (int*)  alloc((size_t)(NN+1)*4);
  int*   cur   = (int*)  alloc((size_t)NN*4);
  int*   eids  = (int*)  alloc((size_t)NE*4);
  float* flags = (float*)alloc((size_t)NN*8);
  u16*   eaw1f = (u16*)  alloc((size_t)65536*2);
  u16*   w1af  = (u16*)  alloc((size_t)65536*2);
  u16*   w1bf  = (u16*)  alloc((size_t)65536*2);
  u16*   w1cf  = (u16*)  alloc((size_t)65536*2);
  u16*   euw2f = (u16*)  alloc((size_t)65536*2);
  float* gG    = (float*)alloc((size_t)NG*768*4);
  float* logits= (float*)alloc((size_t)NG*4);

  // one-time per launch: merged weight repacks + flags, b_e init, CSR
  prep_k<<<224,256,0,stream>>>(ea_w1, eaw1f, eu_w1, w1af, w1bf, w1cf,
                               eu_w2, euw2f, batch, heads, tails, flags);
  initbe_k<<<NE*64/256,256,0,stream>>>(ef, gall, BE);
  scan_k<<<1,256,0,stream>>>(ndeg, offs, cur);
  fill_k<<<NE/256,256,0,stream>>>(recvI, cur, eids);

  // score for iter0 (reads the freshly-built BE)
  gemm_k<MODE_SCORE><<<NE/64,256,0,stream>>>(BE, eaw1f, nullptr, score,
      nullptr, nullptr, ea_b1, ea_w2, ea_b2, nullptr, nullptr, nullptr);

  for (int it=0; it<3; ++it){
    // scatter-softmax + degree-normalized aggregation -> b_v (f32 + bf16)
    agg_k<<<NN/4,256,0,stream>>>(score, BE, offs, eids, bv, bvb);
    // P = r_v@W1a + b1 ; Q = r_v@W1b (one dispatch, grid.y selects half)
    gemm_k<MODE_PQ><<<dim3(NN/64,2),256,0,stream>>>(bvb, w1af, w1bf, nullptr,
        P, Q, eu_b1, nullptr, nullptr, flags, eu_w1 + 256*HD, eu_w1 + 514*HD);
    // fused edge update (+ next score, or final w_e)
    if (it < 2){
      mega_k<false><<<NE/64,256,0,stream>>>(BE, w1cf, euw2f, eaw1f,
          score, nullptr, P, Q, srcI, recvI, eu_b2,
          ea_b1, ea_w2, ea_b2, nullptr, nullptr);
    } else {
      mega_k<true><<<NE/64,256,0,stream>>>(BE, w1cf, euw2f, eaw1f,
          nullptr, out, P, Q, srcI, recvI, eu_b2,
          nullptr, nullptr, nullptr, ew_w, ew_b);
    }
  }

  // graph head (f32 exact, tiny; un-permutes positions)
  gmaxlog_k<<<NG,1024,0,stream>>>(bv, heads, tails, gG,
                                  gw_w1, gw_b1, gw_w2, gw_b2, logits);
  gfin_k<<<1,256,0,stream>>>(gG, logits, out + NE);
}